// Round 2
// baseline (7635.564 us; speedup 1.0000x reference)
//
#include <hip/hip_runtime.h>

#define NB   32
#define CIN  32
#define PL   192
#define CP   96        // channel pairs (PL/2)
#define HH   112
#define WID  112
#define HW   12544     // 112*112
#define COUT 32

// ws float-offset layout
#define W1OFF 64                        // 6144 floats (quantized int values of w1)
#define W2OFF (W1OFF + PL*CIN)          // 1728 floats
#define W3OFF (W2OFF + PL*9)            // 6144 floats
#define Q1OFF_BYTES 65536
#define QBYTES ((size_t)NB*CP*HW)       // 38,535,168 bytes per packed tensor
// scalar slots: wsi[0..3] = float-bits absmax of x,w1,w2,w3
//               wsi[4] = int max of conv1 acc, wsi[5] = int max of conv2 acc
//               wsf[8..11] = scales sx, sw1, sw2, sw3

__device__ __forceinline__ float quant87(float v, float s) {
  return fminf(fmaxf(rintf(v / s), -8.0f), 7.0f);
}

__global__ void kzero(int* __restrict__ wsi) {
  if (threadIdx.x < 16) wsi[threadIdx.x] = 0;
}

__global__ void kmax_x(const float* __restrict__ x, int n4, int* __restrict__ slot) {
  const float4* x4 = (const float4*)x;
  float m = 0.f;
  for (int i = blockIdx.x * blockDim.x + threadIdx.x; i < n4; i += gridDim.x * blockDim.x) {
    float4 v = x4[i];
    m = fmaxf(fmaxf(fabsf(v.x), fabsf(v.y)), fmaxf(fmaxf(fabsf(v.z), fabsf(v.w)), m));
  }
  for (int o = 32; o; o >>= 1) m = fmaxf(m, __shfl_down(m, o));
  if ((threadIdx.x & 63) == 0) atomicMax(slot, __float_as_int(m));
}

__global__ void kmax_w(const float* __restrict__ w1, const float* __restrict__ w2,
                       const float* __restrict__ w3, int* __restrict__ slots) {
  const float* p; int n;
  if (blockIdx.x == 0)      { p = w1; n = PL * CIN; }
  else if (blockIdx.x == 1) { p = w2; n = PL * 9; }
  else                      { p = w3; n = COUT * PL; }
  float m = 0.f;
  for (int i = threadIdx.x; i < n; i += blockDim.x) m = fmaxf(m, fabsf(p[i]));
  for (int o = 32; o; o >>= 1) m = fmaxf(m, __shfl_down(m, o));
  if ((threadIdx.x & 63) == 0) atomicMax(slots + 1 + blockIdx.x, __float_as_int(m));
}

__global__ void kprep(const float* __restrict__ w1, const float* __restrict__ w2,
                      const float* __restrict__ w3, float* __restrict__ wsf) {
  int* wsi = (int*)wsf;
  __shared__ float ss[4];
  if (threadIdx.x == 0) {
    float sx  = fmaxf(__int_as_float(wsi[0]) / 7.0f, 1e-8f);
    float sw1 = fmaxf(__int_as_float(wsi[1]) / 7.0f, 1e-8f);
    float sw2 = fmaxf(__int_as_float(wsi[2]) / 7.0f, 1e-8f);
    float sw3 = fmaxf(__int_as_float(wsi[3]) / 7.0f, 1e-8f);
    wsf[8] = sx; wsf[9] = sw1; wsf[10] = sw2; wsf[11] = sw3;
    ss[1] = sw1; ss[2] = sw2; ss[3] = sw3;
  }
  __syncthreads();
  float sw1 = ss[1], sw2 = ss[2], sw3 = ss[3];
  for (int i = threadIdx.x; i < PL * CIN; i += blockDim.x)  wsf[W1OFF + i] = quant87(w1[i], sw1);
  for (int i = threadIdx.x; i < PL * 9; i += blockDim.x)    wsf[W2OFF + i] = quant87(w2[i], sw2);
  for (int i = threadIdx.x; i < COUT * PL; i += blockDim.x) wsf[W3OFF + i] = quant87(w3[i], sw3);
}

// conv1 1x1 expand 32->192 + relu. STORE=0: track global int max only.
// STORE=1: quantize via LDS LUT, pack 2 channels/byte, write q1.
template <int STORE>
__launch_bounds__(256)
__global__ void kconv1(const float* __restrict__ x, const float* __restrict__ wsf,
                       unsigned char* __restrict__ q1, int* __restrict__ maxslot) {
  __shared__ float w[PL * CIN];          // 24 KB
  __shared__ unsigned char lut[2176];    // conv1 acc domain [0, 2048]
  const int* wsi = (const int*)wsf;
  for (int i = threadIdx.x; i < PL * CIN; i += 256) w[i] = wsf[W1OFF + i];
  float sx = wsf[8];
  if (STORE) {
    float S1 = wsf[8] * wsf[9];
    float sh1 = fmaxf((S1 * (float)wsi[4]) / 7.0f, 1e-8f);
    for (int i = threadIdx.x; i < 2176; i += 256) {
      float q = rintf((S1 * (float)i) / sh1);        // exact IEEE div, matches per-elem quant
      lut[i] = (unsigned char)fminf(q, 7.0f);
    }
  }
  __syncthreads();
  int gid = blockIdx.x * 256 + threadIdx.x;          // [0, NB*HW); blocks never straddle n
  int n = gid / HW, pos = gid - n * HW;
  const float* xp = x + (size_t)n * CIN * HW + pos;
  float xi[CIN];
#pragma unroll
  for (int c = 0; c < CIN; ++c) xi[c] = quant87(xp[c * HW], sx);
  if (!STORE) {
    int lmax = 0;
    for (int co = 0; co < PL; ++co) {
      float acc = 0.f;
      const float* wr = &w[co * CIN];
#pragma unroll
      for (int c = 0; c < CIN; ++c) acc = fmaf(xi[c], wr[c], acc);
      lmax = max(lmax, (int)fmaxf(acc, 0.f));
    }
    for (int o = 32; o; o >>= 1) lmax = max(lmax, __shfl_down(lmax, o));
    if ((threadIdx.x & 63) == 0) atomicMax(maxslot, lmax);
  } else {
    unsigned char* qp = q1 + (size_t)n * CP * HW + pos;
    for (int cp = 0; cp < CP; ++cp) {
      float a0 = 0.f, a1 = 0.f;
      const float* w0 = &w[(2 * cp) * CIN];
      const float* w1r = &w[(2 * cp + 1) * CIN];
#pragma unroll
      for (int c = 0; c < CIN; ++c) a0 = fmaf(xi[c], w0[c], a0);
#pragma unroll
      for (int c = 0; c < CIN; ++c) a1 = fmaf(xi[c], w1r[c], a1);
      int i0 = (int)fmaxf(a0, 0.f);
      int i1 = (int)fmaxf(a1, 0.f);
      qp[(size_t)cp * HW] = (unsigned char)(lut[i0] | (lut[i1] << 4));
    }
  }
}

// depthwise 3x3 + relu on packed q1 (2 channels per thread).
// STORE=0: global int max. STORE=1: quantize via LUT, write packed q2.
template <int STORE>
__launch_bounds__(256)
__global__ void kconv2(const unsigned char* __restrict__ q1, const float* __restrict__ wsf,
                       unsigned char* __restrict__ q2, int* __restrict__ maxslot) {
  const int* wsi = (const int*)wsf;
  __shared__ unsigned char lut[512];     // conv2 acc domain [0, 504]
  if (STORE) {
    float S1 = wsf[8] * wsf[9];
    float sh1 = fmaxf((S1 * (float)wsi[4]) / 7.0f, 1e-8f);
    float S2 = sh1 * wsf[10];
    float sh2 = fmaxf((S2 * (float)wsi[5]) / 7.0f, 1e-8f);
    for (int i = threadIdx.x; i < 512; i += 256) {
      float q = rintf((S2 * (float)i) / sh2);
      lut[i] = (unsigned char)fminf(q, 7.0f);
    }
    __syncthreads();
  }
  int gid = blockIdx.x * 256 + threadIdx.x;          // [0, NB*CP*HW)
  int pos = gid % HW;
  int ncp = gid / HW;                                // n*CP + cp
  int ch2 = (ncp % CP) * 2;
  int y = pos / WID, xc = pos - y * WID;
  float wv0[9], wv1[9];
  const float* wq = wsf + W2OFF + ch2 * 9;
#pragma unroll
  for (int t = 0; t < 9; ++t) { wv0[t] = wq[t]; wv1[t] = wq[9 + t]; }
  const unsigned char* hp = q1 + (size_t)ncp * HW;
  float a0 = 0.f, a1 = 0.f;
#pragma unroll
  for (int ky = 0; ky < 3; ++ky) {
    int yy = y + ky - 1;
    if ((unsigned)yy >= HH) continue;
#pragma unroll
    for (int kx = 0; kx < 3; ++kx) {
      int xx = xc + kx - 1;
      if ((unsigned)xx >= WID) continue;
      unsigned char b = hp[yy * WID + xx];
      a0 = fmaf((float)(b & 15), wv0[ky * 3 + kx], a0);
      a1 = fmaf((float)(b >> 4), wv1[ky * 3 + kx], a1);
    }
  }
  int i0 = (int)fmaxf(a0, 0.f);
  int i1 = (int)fmaxf(a1, 0.f);
  if (!STORE) {
    int lmax = max(i0, i1);
    for (int o = 32; o; o >>= 1) lmax = max(lmax, __shfl_down(lmax, o));
    if ((threadIdx.x & 63) == 0) atomicMax(maxslot, lmax);
  } else {
    q2[gid] = (unsigned char)(lut[i0] | (lut[i1] << 4));
  }
}

// conv3 1x1 project 192->32 + residual add
__launch_bounds__(256)
__global__ void kconv3(const unsigned char* __restrict__ q2, const float* __restrict__ x,
                       const float* __restrict__ wsf, float* __restrict__ out) {
  __shared__ float w[COUT * PL];         // 24 KB
  for (int i = threadIdx.x; i < COUT * PL; i += 256) w[i] = wsf[W3OFF + i];
  const int* wsi = (const int*)wsf;
  float S1 = wsf[8] * wsf[9];
  float sh1 = fmaxf((S1 * (float)wsi[4]) / 7.0f, 1e-8f);
  float S2 = sh1 * wsf[10];
  float sh2 = fmaxf((S2 * (float)wsi[5]) / 7.0f, 1e-8f);
  float S3 = sh2 * wsf[11];
  __syncthreads();
  int gid = blockIdx.x * 256 + threadIdx.x;          // [0, NB*HW)
  int n = gid / HW, pos = gid - n * HW;
  const unsigned char* hp = q2 + (size_t)n * CP * HW + pos;
  float acc[COUT];
#pragma unroll
  for (int co = 0; co < COUT; ++co) acc[co] = 0.f;
#pragma unroll 4
  for (int cp = 0; cp < CP; ++cp) {
    unsigned char b = hp[(size_t)cp * HW];
    float v0 = (float)(b & 15);
    float v1 = (float)(b >> 4);
    const float* wr = &w[2 * cp];
#pragma unroll
    for (int co = 0; co < COUT; ++co)
      acc[co] = fmaf(v1, wr[co * PL + 1], fmaf(v0, wr[co * PL], acc[co]));
  }
  const float* xp = x + (size_t)n * COUT * HW + pos;
  float* op = out + (size_t)n * COUT * HW + pos;
#pragma unroll
  for (int co = 0; co < COUT; ++co)
    op[co * HW] = S3 * acc[co] + xp[co * HW];
}

extern "C" void kernel_launch(void* const* d_in, const int* in_sizes, int n_in,
                              void* d_out, int out_size, void* d_ws, size_t ws_size,
                              hipStream_t stream) {
  const float* x  = (const float*)d_in[0];
  const float* w1 = (const float*)d_in[1];
  const float* w2 = (const float*)d_in[2];
  const float* w3 = (const float*)d_in[3];
  float* out = (float*)d_out;

  float* wsf = (float*)d_ws;
  int* wsi = (int*)d_ws;
  unsigned char* q1 = (unsigned char*)d_ws + Q1OFF_BYTES;
  unsigned char* q2 = q1 + QBYTES;

  kzero<<<1, 64, 0, stream>>>(wsi);

  int n4 = in_sizes[0] / 4;                        // 3,211,264 float4
  kmax_x<<<1024, 256, 0, stream>>>(x, n4, wsi + 0);
  kmax_w<<<3, 256, 0, stream>>>(w1, w2, w3, wsi);
  kprep<<<1, 256, 0, stream>>>(w1, w2, w3, wsf);

  int npos = NB * HW;                              // 401,408
  kconv1<0><<<npos / 256, 256, 0, stream>>>(x, wsf, q1, wsi + 4);
  kconv1<1><<<npos / 256, 256, 0, stream>>>(x, wsf, q1, wsi + 4);

  int nq = (int)(QBYTES / 256);                    // 150,528 blocks
  kconv2<0><<<nq, 256, 0, stream>>>(q1, wsf, q2, wsi + 5);
  kconv2<1><<<nq, 256, 0, stream>>>(q1, wsf, q2, wsi + 5);

  kconv3<<<npos / 256, 256, 0, stream>>>(q2, x, wsf, out);
}

// Round 3
// 943.344 us; speedup vs baseline: 8.0941x; 8.0941x over previous
//
#include <hip/hip_runtime.h>

#define NB   32
#define CIN  32
#define PL   192
#define CP   96        // channel pairs (PL/2)
#define HH   112
#define WID  112
#define HW   12544     // 112*112
#define COUT 32

// ws float-offset layout
#define W1OFF 64                        // 6144 floats (quantized int values of w1)
#define W2OFF (W1OFF + PL*CIN)          // 1728 floats
#define W3OFF (W2OFF + PL*9)            // 6144 floats
#define Q1OFF_BYTES 65536
#define QBYTES ((size_t)NB*CP*HW)       // 38,535,168 bytes per packed tensor
// scalar slots: wsi[0..3] = float-bits absmax of x,w1,w2,w3
//               wsi[4] = int max of conv1 acc, wsi[5] = int max of conv2 acc
//               wsf[8..11] = scales sx, sw1, sw2, sw3

__device__ __forceinline__ float quant87(float v, float s) {
  return fminf(fmaxf(rintf(v / s), -8.0f), 7.0f);
}

// block-level int max -> single conditional atomic (monotone max: race-safe)
__device__ __forceinline__ void block_max_commit(int lmax, int* __restrict__ slot) {
  __shared__ int red[4];
  for (int o = 32; o; o >>= 1) lmax = max(lmax, __shfl_down(lmax, o));
  if ((threadIdx.x & 63) == 0) red[threadIdx.x >> 6] = lmax;
  __syncthreads();
  if (threadIdx.x == 0) {
    int m = max(max(red[0], red[1]), max(red[2], red[3]));
    int cur = *(const volatile int*)slot;   // cheap broadcast read
    if (m > cur) atomicMax(slot, m);        // few blocks actually atomic
  }
}

__global__ void kzero(int* __restrict__ wsi) {
  if (threadIdx.x < 16) wsi[threadIdx.x] = 0;
}

__global__ void kmax_x(const float* __restrict__ x, int n4, int* __restrict__ slot) {
  const float4* x4 = (const float4*)x;
  float m = 0.f;
  for (int i = blockIdx.x * blockDim.x + threadIdx.x; i < n4; i += gridDim.x * blockDim.x) {
    float4 v = x4[i];
    m = fmaxf(fmaxf(fabsf(v.x), fabsf(v.y)), fmaxf(fmaxf(fabsf(v.z), fabsf(v.w)), m));
  }
  // non-negative floats: int compare == float compare
  block_max_commit(__float_as_int(m), slot);
}

__global__ void kmax_w(const float* __restrict__ w1, const float* __restrict__ w2,
                       const float* __restrict__ w3, int* __restrict__ slots) {
  const float* p; int n;
  if (blockIdx.x == 0)      { p = w1; n = PL * CIN; }
  else if (blockIdx.x == 1) { p = w2; n = PL * 9; }
  else                      { p = w3; n = COUT * PL; }
  float m = 0.f;
  for (int i = threadIdx.x; i < n; i += blockDim.x) m = fmaxf(m, fabsf(p[i]));
  for (int o = 32; o; o >>= 1) m = fmaxf(m, __shfl_down(m, o));
  if ((threadIdx.x & 63) == 0) atomicMax(slots + 1 + blockIdx.x, __float_as_int(m));
}

__global__ void kprep(const float* __restrict__ w1, const float* __restrict__ w2,
                      const float* __restrict__ w3, float* __restrict__ wsf) {
  int* wsi = (int*)wsf;
  __shared__ float ss[4];
  if (threadIdx.x == 0) {
    float sx  = fmaxf(__int_as_float(wsi[0]) / 7.0f, 1e-8f);
    float sw1 = fmaxf(__int_as_float(wsi[1]) / 7.0f, 1e-8f);
    float sw2 = fmaxf(__int_as_float(wsi[2]) / 7.0f, 1e-8f);
    float sw3 = fmaxf(__int_as_float(wsi[3]) / 7.0f, 1e-8f);
    wsf[8] = sx; wsf[9] = sw1; wsf[10] = sw2; wsf[11] = sw3;
    ss[1] = sw1; ss[2] = sw2; ss[3] = sw3;
  }
  __syncthreads();
  float sw1 = ss[1], sw2 = ss[2], sw3 = ss[3];
  for (int i = threadIdx.x; i < PL * CIN; i += blockDim.x)  wsf[W1OFF + i] = quant87(w1[i], sw1);
  for (int i = threadIdx.x; i < PL * 9; i += blockDim.x)    wsf[W2OFF + i] = quant87(w2[i], sw2);
  for (int i = threadIdx.x; i < COUT * PL; i += blockDim.x) wsf[W3OFF + i] = quant87(w3[i], sw3);
}

// conv1 1x1 expand 32->192 + relu. STORE=0: track global int max only.
// STORE=1: quantize via LDS LUT, pack 2 channels/byte, write q1.
template <int STORE>
__launch_bounds__(256)
__global__ void kconv1(const float* __restrict__ x, const float* __restrict__ wsf,
                       unsigned char* __restrict__ q1, int* __restrict__ maxslot) {
  __shared__ float w[PL * CIN];          // 24 KB
  __shared__ unsigned char lut[2176];    // conv1 acc domain [0, 2048]
  const int* wsi = (const int*)wsf;
  for (int i = threadIdx.x; i < PL * CIN; i += 256) w[i] = wsf[W1OFF + i];
  float sx = wsf[8];
  if (STORE) {
    float S1 = wsf[8] * wsf[9];
    float sh1 = fmaxf((S1 * (float)wsi[4]) / 7.0f, 1e-8f);
    for (int i = threadIdx.x; i < 2176; i += 256) {
      float q = rintf((S1 * (float)i) / sh1);        // exact IEEE div, matches per-elem quant
      lut[i] = (unsigned char)fminf(q, 7.0f);
    }
  }
  __syncthreads();
  int gid = blockIdx.x * 256 + threadIdx.x;          // [0, NB*HW); blocks never straddle n
  int n = gid / HW, pos = gid - n * HW;
  const float* xp = x + (size_t)n * CIN * HW + pos;
  float xi[CIN];
#pragma unroll
  for (int c = 0; c < CIN; ++c) xi[c] = quant87(xp[c * HW], sx);
  if (!STORE) {
    int lmax = 0;
    for (int co = 0; co < PL; ++co) {
      float acc = 0.f;
      const float* wr = &w[co * CIN];
#pragma unroll
      for (int c = 0; c < CIN; ++c) acc = fmaf(xi[c], wr[c], acc);
      lmax = max(lmax, (int)fmaxf(acc, 0.f));
    }
    block_max_commit(lmax, maxslot);
  } else {
    unsigned char* qp = q1 + (size_t)n * CP * HW + pos;
    for (int cp = 0; cp < CP; ++cp) {
      float a0 = 0.f, a1 = 0.f;
      const float* w0 = &w[(2 * cp) * CIN];
      const float* w1r = &w[(2 * cp + 1) * CIN];
#pragma unroll
      for (int c = 0; c < CIN; ++c) a0 = fmaf(xi[c], w0[c], a0);
#pragma unroll
      for (int c = 0; c < CIN; ++c) a1 = fmaf(xi[c], w1r[c], a1);
      int i0 = (int)fmaxf(a0, 0.f);
      int i1 = (int)fmaxf(a1, 0.f);
      qp[(size_t)cp * HW] = (unsigned char)(lut[i0] | (lut[i1] << 4));
    }
  }
}

// depthwise 3x3 + relu on packed q1 (2 channels per thread).
// STORE=0: global int max (block-reduced). STORE=1: quantize via LUT, write packed q2.
template <int STORE>
__launch_bounds__(256)
__global__ void kconv2(const unsigned char* __restrict__ q1, const float* __restrict__ wsf,
                       unsigned char* __restrict__ q2, int* __restrict__ maxslot) {
  const int* wsi = (const int*)wsf;
  __shared__ unsigned char lut[512];     // conv2 acc domain [0, 504]
  if (STORE) {
    float S1 = wsf[8] * wsf[9];
    float sh1 = fmaxf((S1 * (float)wsi[4]) / 7.0f, 1e-8f);
    float S2 = sh1 * wsf[10];
    float sh2 = fmaxf((S2 * (float)wsi[5]) / 7.0f, 1e-8f);
    for (int i = threadIdx.x; i < 512; i += 256) {
      float q = rintf((S2 * (float)i) / sh2);
      lut[i] = (unsigned char)fminf(q, 7.0f);
    }
    __syncthreads();
  }
  int gid = blockIdx.x * 256 + threadIdx.x;          // [0, NB*CP*HW)
  int pos = gid % HW;
  int ncp = gid / HW;                                // n*CP + cp
  int ch2 = (ncp % CP) * 2;
  int y = pos / WID, xc = pos - y * WID;
  float wv0[9], wv1[9];
  const float* wq = wsf + W2OFF + ch2 * 9;
#pragma unroll
  for (int t = 0; t < 9; ++t) { wv0[t] = wq[t]; wv1[t] = wq[9 + t]; }
  const unsigned char* hp = q1 + (size_t)ncp * HW;
  float a0 = 0.f, a1 = 0.f;
#pragma unroll
  for (int ky = 0; ky < 3; ++ky) {
    int yy = y + ky - 1;
    if ((unsigned)yy >= HH) continue;
#pragma unroll
    for (int kx = 0; kx < 3; ++kx) {
      int xx = xc + kx - 1;
      if ((unsigned)xx >= WID) continue;
      unsigned char b = hp[yy * WID + xx];
      a0 = fmaf((float)(b & 15), wv0[ky * 3 + kx], a0);
      a1 = fmaf((float)(b >> 4), wv1[ky * 3 + kx], a1);
    }
  }
  int i0 = (int)fmaxf(a0, 0.f);
  int i1 = (int)fmaxf(a1, 0.f);
  if (!STORE) {
    block_max_commit(max(i0, i1), maxslot);
  } else {
    q2[gid] = (unsigned char)(lut[i0] | (lut[i1] << 4));
  }
}

// conv3 1x1 project 192->32 + residual add
__launch_bounds__(256)
__global__ void kconv3(const unsigned char* __restrict__ q2, const float* __restrict__ x,
                       const float* __restrict__ wsf, float* __restrict__ out) {
  __shared__ float w[COUT * PL];         // 24 KB
  for (int i = threadIdx.x; i < COUT * PL; i += 256) w[i] = wsf[W3OFF + i];
  const int* wsi = (const int*)wsf;
  float S1 = wsf[8] * wsf[9];
  float sh1 = fmaxf((S1 * (float)wsi[4]) / 7.0f, 1e-8f);
  float S2 = sh1 * wsf[10];
  float sh2 = fmaxf((S2 * (float)wsi[5]) / 7.0f, 1e-8f);
  float S3 = sh2 * wsf[11];
  __syncthreads();
  int gid = blockIdx.x * 256 + threadIdx.x;          // [0, NB*HW)
  int n = gid / HW, pos = gid - n * HW;
  const unsigned char* hp = q2 + (size_t)n * CP * HW + pos;
  float acc[COUT];
#pragma unroll
  for (int co = 0; co < COUT; ++co) acc[co] = 0.f;
#pragma unroll 4
  for (int cp = 0; cp < CP; ++cp) {
    unsigned char b = hp[(size_t)cp * HW];
    float v0 = (float)(b & 15);
    float v1 = (float)(b >> 4);
    const float* wr = &w[2 * cp];
#pragma unroll
    for (int co = 0; co < COUT; ++co)
      acc[co] = fmaf(v1, wr[co * PL + 1], fmaf(v0, wr[co * PL], acc[co]));
  }
  const float* xp = x + (size_t)n * COUT * HW + pos;
  float* op = out + (size_t)n * COUT * HW + pos;
#pragma unroll
  for (int co = 0; co < COUT; ++co)
    op[co * HW] = S3 * acc[co] + xp[co * HW];
}

extern "C" void kernel_launch(void* const* d_in, const int* in_sizes, int n_in,
                              void* d_out, int out_size, void* d_ws, size_t ws_size,
                              hipStream_t stream) {
  const float* x  = (const float*)d_in[0];
  const float* w1 = (const float*)d_in[1];
  const float* w2 = (const float*)d_in[2];
  const float* w3 = (const float*)d_in[3];
  float* out = (float*)d_out;

  float* wsf = (float*)d_ws;
  int* wsi = (int*)d_ws;
  unsigned char* q1 = (unsigned char*)d_ws + Q1OFF_BYTES;
  unsigned char* q2 = q1 + QBYTES;

  kzero<<<1, 64, 0, stream>>>(wsi);

  int n4 = in_sizes[0] / 4;                        // 3,211,264 float4
  kmax_x<<<1024, 256, 0, stream>>>(x, n4, wsi + 0);
  kmax_w<<<3, 256, 0, stream>>>(w1, w2, w3, wsi);
  kprep<<<1, 256, 0, stream>>>(w1, w2, w3, wsf);

  int npos = NB * HW;                              // 401,408
  kconv1<0><<<npos / 256, 256, 0, stream>>>(x, wsf, q1, wsi + 4);
  kconv1<1><<<npos / 256, 256, 0, stream>>>(x, wsf, q1, wsi + 4);

  int nq = (int)(QBYTES / 256);                    // 150,528 blocks
  kconv2<0><<<nq, 256, 0, stream>>>(q1, wsf, q2, wsi + 5);
  kconv2<1><<<nq, 256, 0, stream>>>(q1, wsf, q2, wsi + 5);

  kconv3<<<npos / 256, 256, 0, stream>>>(q2, x, wsf, out);
}

// Round 4
// 556.008 us; speedup vs baseline: 13.7328x; 1.6966x over previous
//
#include <hip/hip_runtime.h>

#define NB   32
#define CIN  32
#define PL   192
#define CP   96        // channel pairs (PL/2)
#define HH   112
#define WID  112
#define HW   12544     // 112*112
#define COUT 32
#define SEGS 784       // HW/16  (16-pixel segments per image)
#define SEGROW 7       // WID/16

// ws float-offset layout
#define W1OFF 64                        // 6144 floats (quantized int values of w1)
#define W2OFF (W1OFF + PL*CIN)          // 1728 floats
#define W3OFF (W2OFF + PL*9)            // 6144 floats
#define Q1OFF_BYTES 65536
#define QBYTES ((size_t)NB*CP*HW)       // 38,535,168 bytes per packed tensor
// scalar slots: wsi[0..3] = float-bits absmax of x,w1,w2,w3
//               wsi[4] = int max of conv1 acc, wsi[5] = int max of conv2 acc
//               wsf[8..11] = scales sx, sw1, sw2, sw3

__device__ __forceinline__ float quant87(float v, float s) {
  return fminf(fmaxf(rintf(v / s), -8.0f), 7.0f);
}

// block-level int max -> single conditional atomic (monotone max: race-safe)
__device__ __forceinline__ void block_max_commit(int lmax, int* __restrict__ slot) {
  __shared__ int red[4];
  for (int o = 32; o; o >>= 1) lmax = max(lmax, __shfl_down(lmax, o));
  if ((threadIdx.x & 63) == 0) red[threadIdx.x >> 6] = lmax;
  __syncthreads();
  if (threadIdx.x == 0) {
    int m = max(max(red[0], red[1]), max(red[2], red[3]));
    int cur = *(const volatile int*)slot;   // cheap broadcast read
    if (m > cur) atomicMax(slot, m);        // few blocks actually atomic
  }
}

__global__ void kzero(int* __restrict__ wsi) {
  if (threadIdx.x < 16) wsi[threadIdx.x] = 0;
}

__global__ void kmax_x(const float* __restrict__ x, int n4, int* __restrict__ slot) {
  const float4* x4 = (const float4*)x;
  float m = 0.f;
  for (int i = blockIdx.x * blockDim.x + threadIdx.x; i < n4; i += gridDim.x * blockDim.x) {
    float4 v = x4[i];
    m = fmaxf(fmaxf(fabsf(v.x), fabsf(v.y)), fmaxf(fmaxf(fabsf(v.z), fabsf(v.w)), m));
  }
  // non-negative floats: int compare == float compare
  block_max_commit(__float_as_int(m), slot);
}

__global__ void kmax_w(const float* __restrict__ w1, const float* __restrict__ w2,
                       const float* __restrict__ w3, int* __restrict__ slots) {
  const float* p; int n;
  if (blockIdx.x == 0)      { p = w1; n = PL * CIN; }
  else if (blockIdx.x == 1) { p = w2; n = PL * 9; }
  else                      { p = w3; n = COUT * PL; }
  float m = 0.f;
  for (int i = threadIdx.x; i < n; i += blockDim.x) m = fmaxf(m, fabsf(p[i]));
  for (int o = 32; o; o >>= 1) m = fmaxf(m, __shfl_down(m, o));
  if ((threadIdx.x & 63) == 0) atomicMax(slots + 1 + blockIdx.x, __float_as_int(m));
}

__global__ void kprep(const float* __restrict__ w1, const float* __restrict__ w2,
                      const float* __restrict__ w3, float* __restrict__ wsf) {
  int* wsi = (int*)wsf;
  __shared__ float ss[4];
  if (threadIdx.x == 0) {
    float sx  = fmaxf(__int_as_float(wsi[0]) / 7.0f, 1e-8f);
    float sw1 = fmaxf(__int_as_float(wsi[1]) / 7.0f, 1e-8f);
    float sw2 = fmaxf(__int_as_float(wsi[2]) / 7.0f, 1e-8f);
    float sw3 = fmaxf(__int_as_float(wsi[3]) / 7.0f, 1e-8f);
    wsf[8] = sx; wsf[9] = sw1; wsf[10] = sw2; wsf[11] = sw3;
    ss[1] = sw1; ss[2] = sw2; ss[3] = sw3;
  }
  __syncthreads();
  float sw1 = ss[1], sw2 = ss[2], sw3 = ss[3];
  for (int i = threadIdx.x; i < PL * CIN; i += blockDim.x)  wsf[W1OFF + i] = quant87(w1[i], sw1);
  for (int i = threadIdx.x; i < PL * 9; i += blockDim.x)    wsf[W2OFF + i] = quant87(w2[i], sw2);
  for (int i = threadIdx.x; i < COUT * PL; i += blockDim.x) wsf[W3OFF + i] = quant87(w3[i], sw3);
}

// conv1 1x1 expand 32->192 + relu. STORE=0: track global int max only.
// STORE=1: quantize via LDS LUT, pack 2 channels/byte, write q1.
template <int STORE>
__launch_bounds__(256)
__global__ void kconv1(const float* __restrict__ x, const float* __restrict__ wsf,
                       unsigned char* __restrict__ q1, int* __restrict__ maxslot) {
  __shared__ float w[PL * CIN];          // 24 KB
  __shared__ unsigned char lut[2176];    // conv1 acc domain [0, 2048]
  const int* wsi = (const int*)wsf;
  for (int i = threadIdx.x; i < PL * CIN; i += 256) w[i] = wsf[W1OFF + i];
  float sx = wsf[8];
  if (STORE) {
    float S1 = wsf[8] * wsf[9];
    float sh1 = fmaxf((S1 * (float)wsi[4]) / 7.0f, 1e-8f);
    for (int i = threadIdx.x; i < 2176; i += 256) {
      float q = rintf((S1 * (float)i) / sh1);        // exact IEEE div, matches per-elem quant
      lut[i] = (unsigned char)fminf(q, 7.0f);
    }
  }
  __syncthreads();
  int gid = blockIdx.x * 256 + threadIdx.x;          // [0, NB*HW); blocks never straddle n
  int n = gid / HW, pos = gid - n * HW;
  const float* xp = x + (size_t)n * CIN * HW + pos;
  float xi[CIN];
#pragma unroll
  for (int c = 0; c < CIN; ++c) xi[c] = quant87(xp[c * HW], sx);
  if (!STORE) {
    int lmax = 0;
    for (int co = 0; co < PL; ++co) {
      float acc = 0.f;
      const float* wr = &w[co * CIN];
#pragma unroll
      for (int c = 0; c < CIN; ++c) acc = fmaf(xi[c], wr[c], acc);
      lmax = max(lmax, (int)fmaxf(acc, 0.f));
    }
    block_max_commit(lmax, maxslot);
  } else {
    unsigned char* qp = q1 + (size_t)n * CP * HW + pos;
    for (int cp = 0; cp < CP; ++cp) {
      float a0 = 0.f, a1 = 0.f;
      const float* w0 = &w[(2 * cp) * CIN];
      const float* w1r = &w[(2 * cp + 1) * CIN];
#pragma unroll
      for (int c = 0; c < CIN; ++c) a0 = fmaf(xi[c], w0[c], a0);
#pragma unroll
      for (int c = 0; c < CIN; ++c) a1 = fmaf(xi[c], w1r[c], a1);
      int i0 = (int)fmaxf(a0, 0.f);
      int i1 = (int)fmaxf(a1, 0.f);
      qp[(size_t)cp * HW] = (unsigned char)(lut[i0] | (lut[i1] << 4));
    }
  }
}

// depthwise 3x3 + relu on packed q1 — 16 pixels per thread (one uint4 row segment).
// STORE=0: global int max (block-reduced). STORE=1: quantize via LUT, write packed q2.
template <int STORE>
__launch_bounds__(256)
__global__ void kconv2(const unsigned char* __restrict__ q1, const float* __restrict__ wsf,
                       unsigned char* __restrict__ q2, int* __restrict__ maxslot) {
  const int* wsi = (const int*)wsf;
  __shared__ unsigned char lut[512];     // conv2 acc domain [0, 441]
  if (STORE) {
    float S1 = wsf[8] * wsf[9];
    float sh1 = fmaxf((S1 * (float)wsi[4]) / 7.0f, 1e-8f);
    float S2 = sh1 * wsf[10];
    float sh2 = fmaxf((S2 * (float)wsi[5]) / 7.0f, 1e-8f);
    for (int i = threadIdx.x; i < 512; i += 256) {
      float q = rintf((S2 * (float)i) / sh2);
      lut[i] = (unsigned char)fminf(q, 7.0f);
    }
    __syncthreads();
  }
  int gid = blockIdx.x * 256 + threadIdx.x;          // [0, NB*CP*SEGS)
  int ncp = gid / SEGS;                              // n*CP + cp
  int seg = gid - ncp * SEGS;
  int y = seg / SEGROW;
  int x0 = (seg - y * SEGROW) * 16;
  int ch2 = (ncp % CP) * 2;
  const float* wq = wsf + W2OFF + ch2 * 9;
  float w0r[9], w1r[9];
#pragma unroll
  for (int t = 0; t < 9; ++t) { w0r[t] = wq[t]; w1r[t] = wq[9 + t]; }
  const unsigned char* hp = q1 + (size_t)ncp * HW + x0;
  float a0[16], a1[16];
#pragma unroll
  for (int j = 0; j < 16; ++j) { a0[j] = 0.f; a1[j] = 0.f; }
#pragma unroll
  for (int ky = 0; ky < 3; ++ky) {
    int yy = y + ky - 1;
    if ((unsigned)yy >= HH) continue;
    const unsigned char* rp = hp + yy * WID;
    uint4 u = *(const uint4*)rp;                     // 16 aligned pixel bytes
    unsigned int left  = (x0 > 0)        ? (unsigned int)rp[-1] : 0u;
    unsigned int right = (x0 < WID - 16) ? (unsigned int)rp[16] : 0u;
    float lo[18], hi[18];                            // x = x0-1 .. x0+16
    lo[0]  = (float)(left & 15u);  hi[0]  = (float)(left >> 4);
    unsigned int uu[4] = {u.x, u.y, u.z, u.w};
#pragma unroll
    for (int t = 0; t < 4; ++t) {
#pragma unroll
      for (int k = 0; k < 4; ++k) {
        unsigned int b = (uu[t] >> (8 * k)) & 255u;
        lo[1 + 4 * t + k] = (float)(b & 15u);
        hi[1 + 4 * t + k] = (float)(b >> 4);
      }
    }
    lo[17] = (float)(right & 15u); hi[17] = (float)(right >> 4);
#pragma unroll
    for (int j = 0; j < 16; ++j) {
      float s0 = a0[j], s1 = a1[j];
#pragma unroll
      for (int kx = 0; kx < 3; ++kx) {
        s0 = fmaf(lo[j + kx], w0r[ky * 3 + kx], s0);
        s1 = fmaf(hi[j + kx], w1r[ky * 3 + kx], s1);
      }
      a0[j] = s0; a1[j] = s1;
    }
  }
  if (!STORE) {
    int lmax = 0;
#pragma unroll
    for (int j = 0; j < 16; ++j) {
      lmax = max(lmax, (int)fmaxf(a0[j], 0.f));
      lmax = max(lmax, (int)fmaxf(a1[j], 0.f));
    }
    block_max_commit(lmax, maxslot);
  } else {
    unsigned int ow[4] = {0u, 0u, 0u, 0u};
#pragma unroll
    for (int j = 0; j < 16; ++j) {
      int i0 = (int)fmaxf(a0[j], 0.f);
      int i1 = (int)fmaxf(a1[j], 0.f);
      unsigned int byte = (unsigned int)lut[i0] | ((unsigned int)lut[i1] << 4);
      ow[j >> 2] |= byte << (8 * (j & 3));
    }
    uint4 o; o.x = ow[0]; o.y = ow[1]; o.z = ow[2]; o.w = ow[3];
    *(uint4*)(q2 + (size_t)ncp * HW + (size_t)y * WID + x0) = o;
  }
}

// conv3 1x1 project 192->32 + residual add
__launch_bounds__(256)
__global__ void kconv3(const unsigned char* __restrict__ q2, const float* __restrict__ x,
                       const float* __restrict__ wsf, float* __restrict__ out) {
  __shared__ float w[COUT * PL];         // 24 KB
  for (int i = threadIdx.x; i < COUT * PL; i += 256) w[i] = wsf[W3OFF + i];
  const int* wsi = (const int*)wsf;
  float S1 = wsf[8] * wsf[9];
  float sh1 = fmaxf((S1 * (float)wsi[4]) / 7.0f, 1e-8f);
  float S2 = sh1 * wsf[10];
  float sh2 = fmaxf((S2 * (float)wsi[5]) / 7.0f, 1e-8f);
  float S3 = sh2 * wsf[11];
  __syncthreads();
  int gid = blockIdx.x * 256 + threadIdx.x;          // [0, NB*HW)
  int n = gid / HW, pos = gid - n * HW;
  const unsigned char* hp = q2 + (size_t)n * CP * HW + pos;
  float acc[COUT];
#pragma unroll
  for (int co = 0; co < COUT; ++co) acc[co] = 0.f;
#pragma unroll 4
  for (int cp = 0; cp < CP; ++cp) {
    unsigned char b = hp[(size_t)cp * HW];
    float v0 = (float)(b & 15);
    float v1 = (float)(b >> 4);
    const float* wr = &w[2 * cp];
#pragma unroll
    for (int co = 0; co < COUT; ++co)
      acc[co] = fmaf(v1, wr[co * PL + 1], fmaf(v0, wr[co * PL], acc[co]));
  }
  const float* xp = x + (size_t)n * COUT * HW + pos;
  float* op = out + (size_t)n * COUT * HW + pos;
#pragma unroll
  for (int co = 0; co < COUT; ++co)
    op[co * HW] = S3 * acc[co] + xp[co * HW];
}

extern "C" void kernel_launch(void* const* d_in, const int* in_sizes, int n_in,
                              void* d_out, int out_size, void* d_ws, size_t ws_size,
                              hipStream_t stream) {
  const float* x  = (const float*)d_in[0];
  const float* w1 = (const float*)d_in[1];
  const float* w2 = (const float*)d_in[2];
  const float* w3 = (const float*)d_in[3];
  float* out = (float*)d_out;

  float* wsf = (float*)d_ws;
  int* wsi = (int*)d_ws;
  unsigned char* q1 = (unsigned char*)d_ws + Q1OFF_BYTES;
  unsigned char* q2 = q1 + QBYTES;

  kzero<<<1, 64, 0, stream>>>(wsi);

  int n4 = in_sizes[0] / 4;                        // 3,211,264 float4
  kmax_x<<<1024, 256, 0, stream>>>(x, n4, wsi + 0);
  kmax_w<<<3, 256, 0, stream>>>(w1, w2, w3, wsi);
  kprep<<<1, 256, 0, stream>>>(w1, w2, w3, wsf);

  int npos = NB * HW;                              // 401,408
  kconv1<0><<<npos / 256, 256, 0, stream>>>(x, wsf, q1, wsi + 4);
  kconv1<1><<<npos / 256, 256, 0, stream>>>(x, wsf, q1, wsi + 4);

  int nseg = NB * CP * SEGS;                       // 2,408,448 threads, 16 px each
  kconv2<0><<<nseg / 256, 256, 0, stream>>>(q1, wsf, q2, wsi + 5);
  kconv2<1><<<nseg / 256, 256, 0, stream>>>(q1, wsf, q2, wsi + 5);

  kconv3<<<npos / 256, 256, 0, stream>>>(q2, x, wsf, out);
}

// Round 5
// 379.382 us; speedup vs baseline: 20.1263x; 1.4656x over previous
//
#include <hip/hip_runtime.h>

#define NB   32
#define CIN  32
#define PL   192
#define CP   96        // channel pairs (PL/2)
#define HH   112
#define WID  112
#define HW   12544     // 112*112
#define COUT 32
#define SEGS 784       // HW/16
#define SEGROW 7       // WID/16
#define PXB  1568      // NB*HW/256 (px-blocks for kconv1)

// ws float-offset layout
#define W1OFF 64                        // w1 transposed [c][192]
#define W2OFF (W1OFF + PL*CIN)          // w2 [ch][9]
#define W3OFF (W2OFF + PL*9)            // w3 transposed [ci][32]
#define Q1OFF_BYTES 65536
#define QBYTES ((size_t)NB*CP*HW)       // 38,535,168 bytes per packed tensor
// scalar slots: wsi[0..3] = float-bits absmax of x,w1,w2,w3
//               wsi[4] = int max of conv1 acc, wsi[5] = int max of conv2 acc
//               wsf[8..11] = scales sx, sw1, sw2, sw3

__device__ __forceinline__ float quant87(float v, float s) {
  return fminf(fmaxf(rintf(v / s), -8.0f), 7.0f);
}

// block-level int max -> single conditional atomic (monotone max: race-safe)
__device__ __forceinline__ void block_max_commit(int lmax, int* __restrict__ slot) {
  __shared__ int red[4];
  for (int o = 32; o; o >>= 1) lmax = max(lmax, __shfl_down(lmax, o));
  if ((threadIdx.x & 63) == 0) red[threadIdx.x >> 6] = lmax;
  __syncthreads();
  if (threadIdx.x == 0) {
    int m = max(max(red[0], red[1]), max(red[2], red[3]));
    int cur = *(const volatile int*)slot;
    if (m > cur) atomicMax(slot, m);
  }
}

__global__ void kzero(int* __restrict__ wsi) {
  if (threadIdx.x < 16) wsi[threadIdx.x] = 0;
}

__global__ void kmax_x(const float* __restrict__ x, int n4, int* __restrict__ slot) {
  const float4* x4 = (const float4*)x;
  float m = 0.f;
  for (int i = blockIdx.x * blockDim.x + threadIdx.x; i < n4; i += gridDim.x * blockDim.x) {
    float4 v = x4[i];
    m = fmaxf(fmaxf(fabsf(v.x), fabsf(v.y)), fmaxf(fmaxf(fabsf(v.z), fabsf(v.w)), m));
  }
  block_max_commit(__float_as_int(m), slot);   // non-negative: int cmp == float cmp
}

__global__ void kmax_w(const float* __restrict__ w1, const float* __restrict__ w2,
                       const float* __restrict__ w3, int* __restrict__ slots) {
  const float* p; int n;
  if (blockIdx.x == 0)      { p = w1; n = PL * CIN; }
  else if (blockIdx.x == 1) { p = w2; n = PL * 9; }
  else                      { p = w3; n = COUT * PL; }
  float m = 0.f;
  for (int i = threadIdx.x; i < n; i += blockDim.x) m = fmaxf(m, fabsf(p[i]));
  for (int o = 32; o; o >>= 1) m = fmaxf(m, __shfl_down(m, o));
  if ((threadIdx.x & 63) == 0) atomicMax(slots + 1 + blockIdx.x, __float_as_int(m));
}

__global__ void kprep(const float* __restrict__ w1, const float* __restrict__ w2,
                      const float* __restrict__ w3, float* __restrict__ wsf) {
  int* wsi = (int*)wsf;
  __shared__ float ss[4];
  if (threadIdx.x == 0) {
    float sx  = fmaxf(__int_as_float(wsi[0]) / 7.0f, 1e-8f);
    float sw1 = fmaxf(__int_as_float(wsi[1]) / 7.0f, 1e-8f);
    float sw2 = fmaxf(__int_as_float(wsi[2]) / 7.0f, 1e-8f);
    float sw3 = fmaxf(__int_as_float(wsi[3]) / 7.0f, 1e-8f);
    wsf[8] = sx; wsf[9] = sw1; wsf[10] = sw2; wsf[11] = sw3;
    ss[1] = sw1; ss[2] = sw2; ss[3] = sw3;
  }
  __syncthreads();
  float sw1 = ss[1], sw2 = ss[2], sw3 = ss[3];
  // w1 transposed: [c][192]
  for (int i = threadIdx.x; i < PL * CIN; i += blockDim.x) {
    int o = i / CIN, c = i - o * CIN;
    wsf[W1OFF + c * PL + o] = quant87(w1[i], sw1);
  }
  for (int i = threadIdx.x; i < PL * 9; i += blockDim.x)
    wsf[W2OFF + i] = quant87(w2[i], sw2);
  // w3 transposed: [ci][32]
  for (int i = threadIdx.x; i < COUT * PL; i += blockDim.x) {
    int o = i / PL, ci = i - o * PL;
    wsf[W3OFF + ci * COUT + o] = quant87(w3[i], sw3);
  }
}

// quantize x once to int8 [n][c][HW]; 16 elems/thread
__launch_bounds__(256)
__global__ void kquantx(const float* __restrict__ x, const float* __restrict__ wsf,
                        signed char* __restrict__ xq) {
  float sx = wsf[8];
  int t = blockIdx.x * 256 + threadIdx.x;          // [0, 802816)
  const float4* xp = (const float4*)x + (size_t)t * 4;
  unsigned int ob[4];
#pragma unroll
  for (int k = 0; k < 4; ++k) {
    float4 v = xp[k];
    int q0 = (int)fminf(fmaxf(rintf(v.x / sx), -8.f), 7.f);
    int q1 = (int)fminf(fmaxf(rintf(v.y / sx), -8.f), 7.f);
    int q2 = (int)fminf(fmaxf(rintf(v.z / sx), -8.f), 7.f);
    int q3 = (int)fminf(fmaxf(rintf(v.w / sx), -8.f), 7.f);
    ob[k] = (q0 & 255) | ((q1 & 255) << 8) | ((q2 & 255) << 16) | ((q3 & 255) << 24);
  }
  uint4 o; o.x = ob[0]; o.y = ob[1]; o.z = ob[2]; o.w = ob[3];
  *(uint4*)(xq + (size_t)t * 16) = o;
}

// conv1 1x1 expand 32->192 + relu, register-tiled: thread = 8 outs x 8 px.
// STORE=0: global int max. STORE=1: LUT-quantize, pack ch-pairs, write q1.
template <int STORE>
__launch_bounds__(256)
__global__ void kconv1(const signed char* __restrict__ xqs, const float* __restrict__ wsf,
                       unsigned char* __restrict__ q1, int* __restrict__ maxslot) {
  __shared__ float lw[CIN * 64];         // this block's 64 outs, [c][64]
  __shared__ unsigned char lut[2176];    // conv1 acc domain [0, 2048]
  const int* wsi = (const int*)wsf;
  int bi = blockIdx.x;
  int ogb = bi / PXB;                    // 0..2 (out-block of 64)
  int pxb = bi - ogb * PXB;              // 0..1567
  for (int i = threadIdx.x; i < CIN * 64; i += 256) {
    int c = i >> 6, ol = i & 63;
    lw[i] = wsf[W1OFF + c * PL + ogb * 64 + ol];
  }
  if (STORE) {
    float S1 = wsf[8] * wsf[9];
    float sh1 = fmaxf((S1 * (float)wsi[4]) / 7.0f, 1e-8f);
    for (int i = threadIdx.x; i < 2176; i += 256)
      lut[i] = (unsigned char)fminf(rintf((S1 * (float)i) / sh1), 7.0f);
  }
  __syncthreads();
  int og_l = threadIdx.x >> 5;           // 0..7
  int pxl = threadIdx.x & 31;            // 0..31
  int gp = pxb * 256 + pxl * 8;          // blocks never straddle n (12544%256==0)
  int n = gp / HW, pos = gp - n * HW;
  const unsigned char* xp = (const unsigned char*)xqs + (size_t)n * CIN * HW + pos;
  float acc[8][8];
#pragma unroll
  for (int o = 0; o < 8; ++o)
#pragma unroll
    for (int j = 0; j < 8; ++j) acc[o][j] = 0.f;
#pragma unroll 4
  for (int c = 0; c < CIN; ++c) {
    uint2 xv = *(const uint2*)(xp + (size_t)c * HW);
    float xf[8];
#pragma unroll
    for (int k = 0; k < 4; ++k) {
      xf[k]     = (float)((int)(xv.x << (24 - 8 * k)) >> 24);
      xf[4 + k] = (float)((int)(xv.y << (24 - 8 * k)) >> 24);
    }
    float wo[8];
    *(float4*)&wo[0] = *(const float4*)&lw[c * 64 + og_l * 8];
    *(float4*)&wo[4] = *(const float4*)&lw[c * 64 + og_l * 8 + 4];
#pragma unroll
    for (int o = 0; o < 8; ++o)
#pragma unroll
      for (int j = 0; j < 8; ++j)
        acc[o][j] = fmaf(xf[j], wo[o], acc[o][j]);
  }
  if (!STORE) {
    int lmax = 0;
#pragma unroll
    for (int o = 0; o < 8; ++o)
#pragma unroll
      for (int j = 0; j < 8; ++j)
        lmax = max(lmax, (int)fmaxf(acc[o][j], 0.f));
    block_max_commit(lmax, maxslot);
  } else {
    int cpb = ogb * 32 + og_l * 4;       // cp base (outs are 8-aligned)
#pragma unroll
    for (int m = 0; m < 4; ++m) {
      unsigned int b0 = 0, b1 = 0;
#pragma unroll
      for (int j = 0; j < 4; ++j) {
        int i0 = (int)fmaxf(acc[2 * m][j], 0.f);
        int i1 = (int)fmaxf(acc[2 * m + 1][j], 0.f);
        b0 |= ((unsigned)(lut[i0] | (lut[i1] << 4))) << (8 * j);
        int i2 = (int)fmaxf(acc[2 * m][4 + j], 0.f);
        int i3 = (int)fmaxf(acc[2 * m + 1][4 + j], 0.f);
        b1 |= ((unsigned)(lut[i2] | (lut[i3] << 4))) << (8 * j);
      }
      uint2 w; w.x = b0; w.y = b1;
      *(uint2*)(q1 + ((size_t)n * CP + cpb + m) * HW + pos) = w;
    }
  }
}

// depthwise 3x3 + relu on packed q1 — 16 pixels per thread (one uint4 row segment).
template <int STORE>
__launch_bounds__(256)
__global__ void kconv2(const unsigned char* __restrict__ q1, const float* __restrict__ wsf,
                       unsigned char* __restrict__ q2, int* __restrict__ maxslot) {
  const int* wsi = (const int*)wsf;
  __shared__ unsigned char lut[512];     // conv2 acc domain [0, 441]
  if (STORE) {
    float S1 = wsf[8] * wsf[9];
    float sh1 = fmaxf((S1 * (float)wsi[4]) / 7.0f, 1e-8f);
    float S2 = sh1 * wsf[10];
    float sh2 = fmaxf((S2 * (float)wsi[5]) / 7.0f, 1e-8f);
    for (int i = threadIdx.x; i < 512; i += 256)
      lut[i] = (unsigned char)fminf(rintf((S2 * (float)i) / sh2), 7.0f);
    __syncthreads();
  }
  int gid = blockIdx.x * 256 + threadIdx.x;          // [0, NB*CP*SEGS)
  int ncp = gid / SEGS;
  int seg = gid - ncp * SEGS;
  int y = seg / SEGROW;
  int x0 = (seg - y * SEGROW) * 16;
  int ch2 = (ncp % CP) * 2;
  const float* wq = wsf + W2OFF + ch2 * 9;
  float w0r[9], w1r[9];
#pragma unroll
  for (int t = 0; t < 9; ++t) { w0r[t] = wq[t]; w1r[t] = wq[9 + t]; }
  const unsigned char* hp = q1 + (size_t)ncp * HW + x0;
  float a0[16], a1[16];
#pragma unroll
  for (int j = 0; j < 16; ++j) { a0[j] = 0.f; a1[j] = 0.f; }
#pragma unroll
  for (int ky = 0; ky < 3; ++ky) {
    int yy = y + ky - 1;
    if ((unsigned)yy >= HH) continue;
    const unsigned char* rp = hp + yy * WID;
    uint4 u = *(const uint4*)rp;
    unsigned int left  = (x0 > 0)        ? (unsigned int)rp[-1] : 0u;
    unsigned int right = (x0 < WID - 16) ? (unsigned int)rp[16] : 0u;
    float lo[18], hi[18];
    lo[0]  = (float)(left & 15u);  hi[0]  = (float)(left >> 4);
    unsigned int uu[4] = {u.x, u.y, u.z, u.w};
#pragma unroll
    for (int t = 0; t < 4; ++t) {
#pragma unroll
      for (int k = 0; k < 4; ++k) {
        unsigned int b = (uu[t] >> (8 * k)) & 255u;
        lo[1 + 4 * t + k] = (float)(b & 15u);
        hi[1 + 4 * t + k] = (float)(b >> 4);
      }
    }
    lo[17] = (float)(right & 15u); hi[17] = (float)(right >> 4);
#pragma unroll
    for (int j = 0; j < 16; ++j) {
      float s0 = a0[j], s1 = a1[j];
#pragma unroll
      for (int kx = 0; kx < 3; ++kx) {
        s0 = fmaf(lo[j + kx], w0r[ky * 3 + kx], s0);
        s1 = fmaf(hi[j + kx], w1r[ky * 3 + kx], s1);
      }
      a0[j] = s0; a1[j] = s1;
    }
  }
  if (!STORE) {
    int lmax = 0;
#pragma unroll
    for (int j = 0; j < 16; ++j) {
      lmax = max(lmax, (int)fmaxf(a0[j], 0.f));
      lmax = max(lmax, (int)fmaxf(a1[j], 0.f));
    }
    block_max_commit(lmax, maxslot);
  } else {
    unsigned int ow[4] = {0u, 0u, 0u, 0u};
#pragma unroll
    for (int j = 0; j < 16; ++j) {
      int i0 = (int)fmaxf(a0[j], 0.f);
      int i1 = (int)fmaxf(a1[j], 0.f);
      unsigned int byte = (unsigned int)lut[i0] | ((unsigned int)lut[i1] << 4);
      ow[j >> 2] |= byte << (8 * (j & 3));
    }
    uint4 o; o.x = ow[0]; o.y = ow[1]; o.z = ow[2]; o.w = ow[3];
    *(uint4*)(q2 + (size_t)ncp * HW + (size_t)y * WID + x0) = o;
  }
}

// conv3 1x1 project 192->32 + residual, register-tiled: thread = 8 outs x 8 px
__launch_bounds__(256)
__global__ void kconv3(const unsigned char* __restrict__ q2, const float* __restrict__ x,
                       const float* __restrict__ wsf, float* __restrict__ out) {
  __shared__ float lw[PL * COUT];        // 24 KB, [ci][32]
  for (int i = threadIdx.x; i < PL * COUT; i += 256) lw[i] = wsf[W3OFF + i];
  const int* wsi = (const int*)wsf;
  float S1 = wsf[8] * wsf[9];
  float sh1 = fmaxf((S1 * (float)wsi[4]) / 7.0f, 1e-8f);
  float S2 = sh1 * wsf[10];
  float sh2 = fmaxf((S2 * (float)wsi[5]) / 7.0f, 1e-8f);
  float S3 = sh2 * wsf[11];
  __syncthreads();
  int og = threadIdx.x >> 6;             // wave index (uniform per wave)
  int pxl = threadIdx.x & 63;
  int gp = blockIdx.x * 512 + pxl * 8;   // per-lane n handles image straddle
  int n = gp / HW, pos = gp - n * HW;
  int ob = og * 8;
  const unsigned char* qp = q2 + (size_t)n * CP * HW + pos;
  float acc[8][8];
#pragma unroll
  for (int o = 0; o < 8; ++o)
#pragma unroll
    for (int j = 0; j < 8; ++j) acc[o][j] = 0.f;
#pragma unroll 2
  for (int cp = 0; cp < CP; ++cp) {
    uint2 qv = *(const uint2*)(qp + (size_t)cp * HW);
    float lo[8], hi[8];
#pragma unroll
    for (int k = 0; k < 4; ++k) {
      lo[k]     = (float)((qv.x >> (8 * k)) & 15u);
      hi[k]     = (float)((qv.x >> (8 * k + 4)) & 15u);
      lo[4 + k] = (float)((qv.y >> (8 * k)) & 15u);
      hi[4 + k] = (float)((qv.y >> (8 * k + 4)) & 15u);
    }
    float w0[8], w1[8];
    *(float4*)&w0[0] = *(const float4*)&lw[(2 * cp) * 32 + ob];
    *(float4*)&w0[4] = *(const float4*)&lw[(2 * cp) * 32 + ob + 4];
    *(float4*)&w1[0] = *(const float4*)&lw[(2 * cp + 1) * 32 + ob];
    *(float4*)&w1[4] = *(const float4*)&lw[(2 * cp + 1) * 32 + ob + 4];
#pragma unroll
    for (int o = 0; o < 8; ++o)
#pragma unroll
      for (int j = 0; j < 8; ++j)
        acc[o][j] = fmaf(hi[j], w1[o], fmaf(lo[j], w0[o], acc[o][j]));
  }
#pragma unroll
  for (int o = 0; o < 8; ++o) {
    const float* xp = x + ((size_t)n * COUT + ob + o) * HW + pos;
    float* op = out + ((size_t)n * COUT + ob + o) * HW + pos;
    float4 x0 = *(const float4*)xp;
    float4 x1 = *(const float4*)(xp + 4);
    float4 r0, r1;
    r0.x = fmaf(S3, acc[o][0], x0.x);
    r0.y = fmaf(S3, acc[o][1], x0.y);
    r0.z = fmaf(S3, acc[o][2], x0.z);
    r0.w = fmaf(S3, acc[o][3], x0.w);
    r1.x = fmaf(S3, acc[o][4], x1.x);
    r1.y = fmaf(S3, acc[o][5], x1.y);
    r1.z = fmaf(S3, acc[o][6], x1.z);
    r1.w = fmaf(S3, acc[o][7], x1.w);
    *(float4*)op = r0;
    *(float4*)(op + 4) = r1;
  }
}

extern "C" void kernel_launch(void* const* d_in, const int* in_sizes, int n_in,
                              void* d_out, int out_size, void* d_ws, size_t ws_size,
                              hipStream_t stream) {
  const float* x  = (const float*)d_in[0];
  const float* w1 = (const float*)d_in[1];
  const float* w2 = (const float*)d_in[2];
  const float* w3 = (const float*)d_in[3];
  float* out = (float*)d_out;

  float* wsf = (float*)d_ws;
  int* wsi = (int*)d_ws;
  unsigned char* q1 = (unsigned char*)d_ws + Q1OFF_BYTES;
  unsigned char* q2 = q1 + QBYTES;
  // xq (12.85 MB int8) lives in d_out's front; consumed by kconv1 passes,
  // then kconv3 (the sole final writer) overwrites the whole out buffer.
  signed char* xq = (signed char*)d_out;

  kzero<<<1, 64, 0, stream>>>(wsi);

  int n4 = in_sizes[0] / 4;                        // 3,211,264 float4
  kmax_x<<<1024, 256, 0, stream>>>(x, n4, wsi + 0);
  kmax_w<<<3, 256, 0, stream>>>(w1, w2, w3, wsi);
  kprep<<<1, 256, 0, stream>>>(w1, w2, w3, wsf);
  kquantx<<<3136, 256, 0, stream>>>(x, wsf, xq);   // 802,816 thr x 16 elems

  kconv1<0><<<3 * PXB, 256, 0, stream>>>(xq, wsf, q1, wsi + 4);
  kconv1<1><<<3 * PXB, 256, 0, stream>>>(xq, wsf, q1, wsi + 4);

  int nseg = NB * CP * SEGS;                       // 2,408,448
  kconv2<0><<<nseg / 256, 256, 0, stream>>>(q1, wsf, q2, wsi + 5);
  kconv2<1><<<nseg / 256, 256, 0, stream>>>(q1, wsf, q2, wsi + 5);

  kconv3<<<NB * HW / 512, 256, 0, stream>>>(q2, x, wsf, out);
}

// Round 6
// 364.615 us; speedup vs baseline: 20.9415x; 1.0405x over previous
//
#include <hip/hip_runtime.h>
#include <string.h>

#define NB   32
#define CIN  32
#define PL   192
#define CP   96        // channel pairs (PL/2)
#define HH   112
#define WID  112
#define HW   12544     // 112*112
#define COUT 32
#define SEGS 784       // HW/16
#define SEGROW 7       // WID/16
#define PXB  1568      // NB*HW/256

// ws float-offset layout
#define W2OFF   64                      // 1728 floats: w2q [ch][9]
#define W1HOFF  (64 + PL*9)             // 3072 u32: f16x2 w1 pairs [c2=16][192]
#define W3HOFF  (W1HOFF + 3072)         // 3072 u32: f16x2 w3 pairs [cp=96][32]
#define C1OFF   (W3HOFF + 3072)         // 192 floats: 1032*sum(w1q) per out
#define C3OFF   (C1OFF + 192)           // 32 floats: 1024*sum(w3q) per out
#define Q1OFF_BYTES 65536
#define QBYTES ((size_t)NB*CP*HW)       // 38,535,168 bytes per packed tensor
// scalars: wsi[0..3]=absmax bits x,w1,w2,w3; wsi[4]=conv1 int max; wsi[5]=conv2 int max
//          wsf[8..11]=scales sx,sw1,sw2,sw3

typedef _Float16 half2_t __attribute__((ext_vector_type(2)));

__device__ __forceinline__ float fdot2f(unsigned int a, unsigned int b, float c) {
#if defined(__has_builtin) && __has_builtin(__builtin_amdgcn_fdot2)
  return __builtin_amdgcn_fdot2(__builtin_bit_cast(half2_t, a),
                                __builtin_bit_cast(half2_t, b), c, false);
#else
  half2_t ha = __builtin_bit_cast(half2_t, a);
  half2_t hb = __builtin_bit_cast(half2_t, b);
  return fmaf((float)ha[1], (float)hb[1], fmaf((float)ha[0], (float)hb[0], c));
#endif
}

__device__ __forceinline__ float quant87(float v, float s) {
  return fminf(fmaxf(rintf(v / s), -8.0f), 7.0f);
}

__device__ __forceinline__ unsigned int packh2(float a, float b) {
  unsigned short ua = __builtin_bit_cast(unsigned short, (_Float16)a);
  unsigned short ub = __builtin_bit_cast(unsigned short, (_Float16)b);
  return (unsigned int)ua | ((unsigned int)ub << 16);
}

__device__ __forceinline__ void block_max_commit(int lmax, int* __restrict__ slot) {
  __shared__ int red[4];
  for (int o = 32; o; o >>= 1) lmax = max(lmax, __shfl_down(lmax, o));
  if ((threadIdx.x & 63) == 0) red[threadIdx.x >> 6] = lmax;
  __syncthreads();
  if (threadIdx.x == 0) {
    int m = max(max(red[0], red[1]), max(red[2], red[3]));
    int cur = *(const volatile int*)slot;
    if (m > cur) atomicMax(slot, m);
  }
}

__global__ void kzero(int* __restrict__ wsi) {
  if (threadIdx.x < 16) wsi[threadIdx.x] = 0;
}

__global__ void kmax_x(const float* __restrict__ x, int n4, int* __restrict__ slot) {
  const float4* x4 = (const float4*)x;
  float m = 0.f;
  for (int i = blockIdx.x * blockDim.x + threadIdx.x; i < n4; i += gridDim.x * blockDim.x) {
    float4 v = x4[i];
    m = fmaxf(fmaxf(fabsf(v.x), fabsf(v.y)), fmaxf(fmaxf(fabsf(v.z), fabsf(v.w)), m));
  }
  block_max_commit(__float_as_int(m), slot);
}

__global__ void kmax_w(const float* __restrict__ w1, const float* __restrict__ w2,
                       const float* __restrict__ w3, int* __restrict__ slots) {
  const float* p; int n;
  if (blockIdx.x == 0)      { p = w1; n = PL * CIN; }
  else if (blockIdx.x == 1) { p = w2; n = PL * 9; }
  else                      { p = w3; n = COUT * PL; }
  float m = 0.f;
  for (int i = threadIdx.x; i < n; i += blockDim.x) m = fmaxf(m, fabsf(p[i]));
  for (int o = 32; o; o >>= 1) m = fmaxf(m, __shfl_down(m, o));
  if ((threadIdx.x & 63) == 0) atomicMax(slots + 1 + blockIdx.x, __float_as_int(m));
}

__global__ void kprep(const float* __restrict__ w1, const float* __restrict__ w2,
                      const float* __restrict__ w3, float* __restrict__ wsf) {
  int* wsi = (int*)wsf;
  unsigned int* wsu = (unsigned int*)wsf;
  __shared__ float ss[4];
  if (threadIdx.x == 0) {
    float sx  = fmaxf(__int_as_float(wsi[0]) / 7.0f, 1e-8f);
    float sw1 = fmaxf(__int_as_float(wsi[1]) / 7.0f, 1e-8f);
    float sw2 = fmaxf(__int_as_float(wsi[2]) / 7.0f, 1e-8f);
    float sw3 = fmaxf(__int_as_float(wsi[3]) / 7.0f, 1e-8f);
    wsf[8] = sx; wsf[9] = sw1; wsf[10] = sw2; wsf[11] = sw3;
    ss[1] = sw1; ss[2] = sw2; ss[3] = sw3;
  }
  __syncthreads();
  float sw1 = ss[1], sw2 = ss[2], sw3 = ss[3];
  // w1 f16x2 pairs [c2][192 outs]
  for (int i = threadIdx.x; i < 16 * PL; i += blockDim.x) {
    int c2 = i / PL, o = i - c2 * PL;
    float a = quant87(w1[o * CIN + 2 * c2], sw1);
    float b = quant87(w1[o * CIN + 2 * c2 + 1], sw1);
    wsu[W1HOFF + i] = packh2(a, b);
  }
  // corr1 = 1032 * sum_c w1q
  for (int o = threadIdx.x; o < PL; o += blockDim.x) {
    float s = 0.f;
    for (int c = 0; c < CIN; ++c) s += quant87(w1[o * CIN + c], sw1);
    wsf[C1OFF + o] = 1032.0f * s;
  }
  for (int i = threadIdx.x; i < PL * 9; i += blockDim.x)
    wsf[W2OFF + i] = quant87(w2[i], sw2);
  // w3 f16x2 pairs [cp][32 outs]
  for (int i = threadIdx.x; i < CP * COUT; i += blockDim.x) {
    int cp = i / COUT, o = i - cp * COUT;
    float a = quant87(w3[o * PL + 2 * cp], sw3);
    float b = quant87(w3[o * PL + 2 * cp + 1], sw3);
    wsu[W3HOFF + i] = packh2(a, b);
  }
  // corr3 = 1024 * sum_k w3q
  for (int o = threadIdx.x; o < COUT; o += blockDim.x) {
    float s = 0.f;
    for (int k = 0; k < PL; ++k) s += quant87(w3[o * PL + k], sw3);
    wsf[C3OFF + o] = 1024.0f * s;
  }
}

// quantize x to channel-pair-packed nibbles [n][c2=16][HW]; byte = (q_even+8)|(q_odd+8)<<4
__launch_bounds__(256)
__global__ void kquantx(const float* __restrict__ x, const float* __restrict__ wsf,
                        unsigned char* __restrict__ xq) {
  float sx = wsf[8];
  int t = blockIdx.x * 256 + threadIdx.x;            // [0, NB*16*SEGS)
  int s = t % SEGS;
  int c2 = (t / SEGS) % 16;
  int n = t / (SEGS * 16);
  const float* r0 = x + ((size_t)n * CIN + 2 * c2) * HW + s * 16;
  const float* r1 = r0 + HW;
  unsigned int ob[4];
#pragma unroll
  for (int k = 0; k < 4; ++k) {
    float4 v0 = *(const float4*)(r0 + 4 * k);
    float4 v1 = *(const float4*)(r1 + 4 * k);
    int a0 = (int)quant87(v0.x, sx) + 8, b0 = (int)quant87(v1.x, sx) + 8;
    int a1 = (int)quant87(v0.y, sx) + 8, b1 = (int)quant87(v1.y, sx) + 8;
    int a2 = (int)quant87(v0.z, sx) + 8, b2 = (int)quant87(v1.z, sx) + 8;
    int a3 = (int)quant87(v0.w, sx) + 8, b3 = (int)quant87(v1.w, sx) + 8;
    ob[k] = (unsigned)(a0 | (b0 << 4) | ((a1 | (b1 << 4)) << 8) |
                       ((a2 | (b2 << 4)) << 16) | ((a3 | (b3 << 4)) << 24));
  }
  uint4 o; o.x = ob[0]; o.y = ob[1]; o.z = ob[2]; o.w = ob[3];
  *(uint4*)(xq + ((size_t)n * 16 + c2) * HW + s * 16) = o;
}

// conv1 1x1 expand 32->192 + relu via dot2. thread = 8 outs x 8 px.
template <int STORE>
__launch_bounds__(256)
__global__ void kconv1(const unsigned char* __restrict__ xq, const float* __restrict__ wsf,
                       unsigned char* __restrict__ q1, int* __restrict__ maxslot) {
  __shared__ unsigned int lw[16 * 64];   // f16x2 pairs for this block's 64 outs
  __shared__ float corrl[64];
  __shared__ unsigned char lut[2176];
  const int* wsi = (const int*)wsf;
  const unsigned int* wsu = (const unsigned int*)wsf;
  int ogb = blockIdx.x / PXB;            // 0..2
  int pxb = blockIdx.x - ogb * PXB;
  for (int i = threadIdx.x; i < 1024; i += 256)
    lw[i] = wsu[W1HOFF + (i >> 6) * PL + ogb * 64 + (i & 63)];
  if (threadIdx.x < 64) corrl[threadIdx.x] = wsf[C1OFF + ogb * 64 + threadIdx.x];
  if (STORE) {
    float S1 = wsf[8] * wsf[9];
    float sh1 = fmaxf((S1 * (float)wsi[4]) / 7.0f, 1e-8f);
    for (int i = threadIdx.x; i < 2176; i += 256)
      lut[i] = (unsigned char)fminf(rintf((S1 * (float)i) / sh1), 7.0f);
  }
  __syncthreads();
  int og = threadIdx.x >> 5;             // 0..7
  int pxl = threadIdx.x & 31;
  int gp = pxb * 256 + pxl * 8;          // blocks never straddle n
  int n = gp / HW, pos = gp - n * HW;
  const unsigned char* xp = xq + (size_t)n * 16 * HW + pos;
  float acc[8][8];
#pragma unroll
  for (int o = 0; o < 8; ++o)
#pragma unroll
    for (int j = 0; j < 8; ++j) acc[o][j] = 0.f;
#pragma unroll 2
  for (int c2 = 0; c2 < 16; ++c2) {
    uint2 xv = *(const uint2*)(xp + (size_t)c2 * HW);
    unsigned int pw[8];
#pragma unroll
    for (int k = 0; k < 4; ++k) {
      unsigned int b0 = (xv.x >> (8 * k)) & 255u;
      unsigned int b1 = (xv.y >> (8 * k)) & 255u;
      pw[k]     = 0x64006400u | (b0 & 15u) | ((b0 & 0xF0u) << 12);
      pw[4 + k] = 0x64006400u | (b1 & 15u) | ((b1 & 0xF0u) << 12);
    }
    uint4 wa = *(const uint4*)&lw[c2 * 64 + og * 8];
    uint4 wb = *(const uint4*)&lw[c2 * 64 + og * 8 + 4];
    unsigned int wv[8] = {wa.x, wa.y, wa.z, wa.w, wb.x, wb.y, wb.z, wb.w};
#pragma unroll
    for (int o = 0; o < 8; ++o)
#pragma unroll
      for (int j = 0; j < 8; ++j)
        acc[o][j] = fdot2f(pw[j], wv[o], acc[o][j]);
  }
  if (!STORE) {
    int lmax = 0;
#pragma unroll
    for (int o = 0; o < 8; ++o) {
      float c = corrl[og * 8 + o];
#pragma unroll
      for (int j = 0; j < 8; ++j)
        lmax = max(lmax, (int)fmaxf(acc[o][j] - c, 0.f));
    }
    block_max_commit(lmax, maxslot);
  } else {
    int cpb = ogb * 32 + og * 4;
#pragma unroll
    for (int m = 0; m < 4; ++m) {
      float c0 = corrl[og * 8 + 2 * m];
      float c1 = corrl[og * 8 + 2 * m + 1];
      unsigned int b0 = 0, b1 = 0;
#pragma unroll
      for (int j = 0; j < 4; ++j) {
        int i0 = (int)fmaxf(acc[2 * m][j] - c0, 0.f);
        int i1 = (int)fmaxf(acc[2 * m + 1][j] - c1, 0.f);
        b0 |= ((unsigned)(lut[i0] | (lut[i1] << 4))) << (8 * j);
        int i2 = (int)fmaxf(acc[2 * m][4 + j] - c0, 0.f);
        int i3 = (int)fmaxf(acc[2 * m + 1][4 + j] - c1, 0.f);
        b1 |= ((unsigned)(lut[i2] | (lut[i3] << 4))) << (8 * j);
      }
      uint2 w; w.x = b0; w.y = b1;
      *(uint2*)(q1 + ((size_t)n * CP + cpb + m) * HW + pos) = w;
    }
  }
}

// depthwise 3x3 + relu on packed q1 — 16 px/thread (unchanged structure)
template <int STORE>
__launch_bounds__(256)
__global__ void kconv2(const unsigned char* __restrict__ q1, const float* __restrict__ wsf,
                       unsigned char* __restrict__ q2, int* __restrict__ maxslot) {
  const int* wsi = (const int*)wsf;
  __shared__ unsigned char lut[512];
  if (STORE) {
    float S1 = wsf[8] * wsf[9];
    float sh1 = fmaxf((S1 * (float)wsi[4]) / 7.0f, 1e-8f);
    float S2 = sh1 * wsf[10];
    float sh2 = fmaxf((S2 * (float)wsi[5]) / 7.0f, 1e-8f);
    for (int i = threadIdx.x; i < 512; i += 256)
      lut[i] = (unsigned char)fminf(rintf((S2 * (float)i) / sh2), 7.0f);
    __syncthreads();
  }
  int gid = blockIdx.x * 256 + threadIdx.x;
  int ncp = gid / SEGS;
  int seg = gid - ncp * SEGS;
  int y = seg / SEGROW;
  int x0 = (seg - y * SEGROW) * 16;
  int ch2 = (ncp % CP) * 2;
  const float* wq = wsf + W2OFF + ch2 * 9;
  float w0r[9], w1r[9];
#pragma unroll
  for (int t = 0; t < 9; ++t) { w0r[t] = wq[t]; w1r[t] = wq[9 + t]; }
  const unsigned char* hp = q1 + (size_t)ncp * HW + x0;
  float a0[16], a1[16];
#pragma unroll
  for (int j = 0; j < 16; ++j) { a0[j] = 0.f; a1[j] = 0.f; }
#pragma unroll
  for (int ky = 0; ky < 3; ++ky) {
    int yy = y + ky - 1;
    if ((unsigned)yy >= HH) continue;
    const unsigned char* rp = hp + yy * WID;
    uint4 u = *(const uint4*)rp;
    unsigned int left  = (x0 > 0)        ? (unsigned int)rp[-1] : 0u;
    unsigned int right = (x0 < WID - 16) ? (unsigned int)rp[16] : 0u;
    float lo[18], hi[18];
    lo[0]  = (float)(left & 15u);  hi[0]  = (float)(left >> 4);
    unsigned int uu[4] = {u.x, u.y, u.z, u.w};
#pragma unroll
    for (int t = 0; t < 4; ++t) {
#pragma unroll
      for (int k = 0; k < 4; ++k) {
        unsigned int b = (uu[t] >> (8 * k)) & 255u;
        lo[1 + 4 * t + k] = (float)(b & 15u);
        hi[1 + 4 * t + k] = (float)(b >> 4);
      }
    }
    lo[17] = (float)(right & 15u); hi[17] = (float)(right >> 4);
#pragma unroll
    for (int j = 0; j < 16; ++j) {
      float s0 = a0[j], s1 = a1[j];
#pragma unroll
      for (int kx = 0; kx < 3; ++kx) {
        s0 = fmaf(lo[j + kx], w0r[ky * 3 + kx], s0);
        s1 = fmaf(hi[j + kx], w1r[ky * 3 + kx], s1);
      }
      a0[j] = s0; a1[j] = s1;
    }
  }
  if (!STORE) {
    int lmax = 0;
#pragma unroll
    for (int j = 0; j < 16; ++j) {
      lmax = max(lmax, (int)fmaxf(a0[j], 0.f));
      lmax = max(lmax, (int)fmaxf(a1[j], 0.f));
    }
    block_max_commit(lmax, maxslot);
  } else {
    unsigned int ow[4] = {0u, 0u, 0u, 0u};
#pragma unroll
    for (int j = 0; j < 16; ++j) {
      int i0 = (int)fmaxf(a0[j], 0.f);
      int i1 = (int)fmaxf(a1[j], 0.f);
      unsigned int byte = (unsigned int)lut[i0] | ((unsigned int)lut[i1] << 4);
      ow[j >> 2] |= byte << (8 * (j & 3));
    }
    uint4 o; o.x = ow[0]; o.y = ow[1]; o.z = ow[2]; o.w = ow[3];
    *(uint4*)(q2 + (size_t)ncp * HW + (size_t)y * WID + x0) = o;
  }
}

// conv3 1x1 project 192->32 + residual via dot2. thread = 8 outs x 4 px.
__launch_bounds__(256)
__global__ void kconv3(const unsigned char* __restrict__ q2, const float* __restrict__ x,
                       const float* __restrict__ wsf, float* __restrict__ out) {
  __shared__ unsigned int lw3[CP * COUT];  // 12 KB f16x2 pairs [cp][32]
  __shared__ float corr3l[COUT];
  const unsigned int* wsu = (const unsigned int*)wsf;
  for (int i = threadIdx.x; i < CP * COUT; i += 256) lw3[i] = wsu[W3HOFF + i];
  if (threadIdx.x < COUT) corr3l[threadIdx.x] = wsf[C3OFF + threadIdx.x];
  const int* wsi = (const int*)wsf;
  float S1 = wsf[8] * wsf[9];
  float sh1 = fmaxf((S1 * (float)wsi[4]) / 7.0f, 1e-8f);
  float S2 = sh1 * wsf[10];
  float sh2 = fmaxf((S2 * (float)wsi[5]) / 7.0f, 1e-8f);
  float S3 = sh2 * wsf[11];
  __syncthreads();
  int og = threadIdx.x >> 6;             // 0..3 (8 outs each)
  int lane = threadIdx.x & 63;
  int gp = blockIdx.x * 256 + lane * 4;  // 256 | HW -> n uniform per block
  int n = gp / HW, pos = gp - n * HW;
  const unsigned char* qp = q2 + (size_t)n * CP * HW + pos;
  float acc[8][4];
#pragma unroll
  for (int o = 0; o < 8; ++o)
#pragma unroll
    for (int j = 0; j < 4; ++j) acc[o][j] = 0.f;
#pragma unroll 4
  for (int cp = 0; cp < CP; ++cp) {
    unsigned int qv = *(const unsigned int*)(qp + (size_t)cp * HW);
    unsigned int pw[4];
#pragma unroll
    for (int j = 0; j < 4; ++j) {
      unsigned int b = (qv >> (8 * j)) & 255u;
      pw[j] = 0x64006400u | (b & 15u) | ((b & 0xF0u) << 12);
    }
    uint4 wa = *(const uint4*)&lw3[cp * 32 + og * 8];
    uint4 wb = *(const uint4*)&lw3[cp * 32 + og * 8 + 4];
    unsigned int wv[8] = {wa.x, wa.y, wa.z, wa.w, wb.x, wb.y, wb.z, wb.w};
#pragma unroll
    for (int o = 0; o < 8; ++o)
#pragma unroll
      for (int j = 0; j < 4; ++j)
        acc[o][j] = fdot2f(pw[j], wv[o], acc[o][j]);
  }
  int ob = og * 8;
#pragma unroll
  for (int o = 0; o < 8; ++o) {
    float c = corr3l[ob + o];
    const float* xp = x + ((size_t)n * COUT + ob + o) * HW + pos;
    float* op = out + ((size_t)n * COUT + ob + o) * HW + pos;
    float4 xv = *(const float4*)xp;
    float4 r;
    r.x = fmaf(S3, acc[o][0] - c, xv.x);
    r.y = fmaf(S3, acc[o][1] - c, xv.y);
    r.z = fmaf(S3, acc[o][2] - c, xv.z);
    r.w = fmaf(S3, acc[o][3] - c, xv.w);
    *(float4*)op = r;
  }
}

extern "C" void kernel_launch(void* const* d_in, const int* in_sizes, int n_in,
                              void* d_out, int out_size, void* d_ws, size_t ws_size,
                              hipStream_t stream) {
  const float* x  = (const float*)d_in[0];
  const float* w1 = (const float*)d_in[1];
  const float* w2 = (const float*)d_in[2];
  const float* w3 = (const float*)d_in[3];
  float* out = (float*)d_out;

  float* wsf = (float*)d_ws;
  int* wsi = (int*)d_ws;
  unsigned char* q1 = (unsigned char*)d_ws + Q1OFF_BYTES;
  unsigned char* q2 = q1 + QBYTES;
  // xq (6.4 MB packed nibbles) lives in d_out's front; consumed by kconv1,
  // then kconv3 (sole final writer) overwrites the whole out buffer.
  unsigned char* xq = (unsigned char*)d_out;

  kzero<<<1, 64, 0, stream>>>(wsi);

  int n4 = in_sizes[0] / 4;
  kmax_x<<<1024, 256, 0, stream>>>(x, n4, wsi + 0);
  kmax_w<<<3, 256, 0, stream>>>(w1, w2, w3, wsi);
  kprep<<<1, 256, 0, stream>>>(w1, w2, w3, wsf);
  kquantx<<<NB * 16 * SEGS / 256, 256, 0, stream>>>(x, wsf, xq);

  kconv1<0><<<3 * PXB, 256, 0, stream>>>(xq, wsf, q1, wsi + 4);
  kconv1<1><<<3 * PXB, 256, 0, stream>>>(xq, wsf, q1, wsi + 4);

  int nseg = NB * CP * SEGS;
  kconv2<0><<<nseg / 256, 256, 0, stream>>>(q1, wsf, q2, wsi + 5);
  kconv2<1><<<nseg / 256, 256, 0, stream>>>(q1, wsf, q2, wsi + 5);

  kconv3<<<NB * HW / 256, 256, 0, stream>>>(q2, x, wsf, out);
}

// Round 7
// 205.329 us; speedup vs baseline: 37.1869x; 1.7758x over previous
//
#include <hip/hip_runtime.h>

#define NB   32
#define CIN  32
#define PL   192
#define CP   96        // channel pairs (PL/2)
#define NG1  4         // 8-ch groups in conv1 input (32/8)
#define NG3  24        // 8-ch groups in conv3 input (192/8)
#define HH   112
#define WID  112
#define HW   12544     // 112*112
#define COUT 32
#define SEGS 784       // HW/16
#define SEGROW 7       // WID/16
#define PXB  1568      // NB*HW/256

// ws u32-offset layout
#define W2POFF 64                       // 768 u32: per ch uint4 {row0,row1,row2,0} i8-packed
#define W1NOFF (W2POFF + PL*4)          // 768 u32: w1 8-ch nibble words [g=4][192]
#define W3NOFF (W1NOFF + NG1*PL)        // 768 u32: w3 8-ch nibble words [g=24][32]
#define Q1OFF_BYTES 65536
#define QBYTES ((size_t)NB*CP*HW)       // 38,535,168 bytes per packed tensor
// scalars: wsi[0..3]=absmax bits x,w1,w2,w3; wsi[4]=conv1 int max; wsi[5]=conv2 int max
//          wsf[8..11]=scales sx,sw1,sw2,sw3

__device__ __forceinline__ int sdot4(unsigned int a, unsigned int b, int c) {
#if defined(__has_builtin) && __has_builtin(__builtin_amdgcn_sdot4)
  return __builtin_amdgcn_sdot4((int)a, (int)b, c, false);
#else
#pragma unroll
  for (int i = 0; i < 4; ++i)
    c += ((int)(a << (24 - 8 * i)) >> 24) * ((int)(b << (24 - 8 * i)) >> 24);
  return c;
#endif
}

__device__ __forceinline__ int sdot8(unsigned int a, unsigned int b, int c) {
#if defined(__has_builtin) && __has_builtin(__builtin_amdgcn_sdot8)
  return __builtin_amdgcn_sdot8((int)a, (int)b, c, false);
#else
#pragma unroll
  for (int i = 0; i < 8; ++i)
    c += ((int)(a << (28 - 4 * i)) >> 28) * ((int)(b << (28 - 4 * i)) >> 28);
  return c;
#endif
}

__device__ __forceinline__ float quant87(float v, float s) {
  return fminf(fmaxf(rintf(v / s), -8.0f), 7.0f);
}

// block-level int max -> single conditional atomic (monotone max: race-safe)
__device__ __forceinline__ void block_max_commit(int lmax, int* __restrict__ slot) {
  __shared__ int red[4];
  for (int o = 32; o; o >>= 1) lmax = max(lmax, __shfl_down(lmax, o));
  if ((threadIdx.x & 63) == 0) red[threadIdx.x >> 6] = lmax;
  __syncthreads();
  if (threadIdx.x == 0) {
    int m = max(max(red[0], red[1]), max(red[2], red[3]));
    int cur = *(const volatile int*)slot;
    if (m > cur) atomicMax(slot, m);
  }
}

__global__ void kzero(int* __restrict__ wsi) {
  if (threadIdx.x < 16) wsi[threadIdx.x] = 0;
}

__global__ void kmax_x(const float* __restrict__ x, int n4, int* __restrict__ slot) {
  const float4* x4 = (const float4*)x;
  float m = 0.f;
  for (int i = blockIdx.x * blockDim.x + threadIdx.x; i < n4; i += gridDim.x * blockDim.x) {
    float4 v = x4[i];
    m = fmaxf(fmaxf(fabsf(v.x), fabsf(v.y)), fmaxf(fmaxf(fabsf(v.z), fabsf(v.w)), m));
  }
  block_max_commit(__float_as_int(m), slot);   // non-negative: int cmp == float cmp
}

__global__ void kmax_w(const float* __restrict__ w1, const float* __restrict__ w2,
                       const float* __restrict__ w3, int* __restrict__ slots) {
  const float* p; int n;
  if (blockIdx.x == 0)      { p = w1; n = PL * CIN; }
  else if (blockIdx.x == 1) { p = w2; n = PL * 9; }
  else                      { p = w3; n = COUT * PL; }
  float m = 0.f;
  for (int i = threadIdx.x; i < n; i += blockDim.x) m = fmaxf(m, fabsf(p[i]));
  for (int o = 32; o; o >>= 1) m = fmaxf(m, __shfl_down(m, o));
  if ((threadIdx.x & 63) == 0) atomicMax(slots + 1 + blockIdx.x, __float_as_int(m));
}

__global__ void kprep(const float* __restrict__ w1, const float* __restrict__ w2,
                      const float* __restrict__ w3, float* __restrict__ wsf) {
  int* wsi = (int*)wsf;
  unsigned int* wsu = (unsigned int*)wsf;
  __shared__ float ss[4];
  if (threadIdx.x == 0) {
    float sx  = fmaxf(__int_as_float(wsi[0]) / 7.0f, 1e-8f);
    float sw1 = fmaxf(__int_as_float(wsi[1]) / 7.0f, 1e-8f);
    float sw2 = fmaxf(__int_as_float(wsi[2]) / 7.0f, 1e-8f);
    float sw3 = fmaxf(__int_as_float(wsi[3]) / 7.0f, 1e-8f);
    wsf[8] = sx; wsf[9] = sw1; wsf[10] = sw2; wsf[11] = sw3;
    ss[1] = sw1; ss[2] = sw2; ss[3] = sw3;
  }
  __syncthreads();
  float sw1 = ss[1], sw2 = ss[2], sw3 = ss[3];
  // w1 8-ch nibble words [g][192]
  for (int i = threadIdx.x; i < NG1 * PL; i += blockDim.x) {
    int g = i / PL, o = i - g * PL;
    unsigned int wrd = 0;
    for (int k = 0; k < 8; ++k)
      wrd |= ((unsigned)((int)quant87(w1[o * CIN + 8 * g + k], sw1) & 15)) << (4 * k);
    wsu[W1NOFF + i] = wrd;
  }
  // w2 i8 row words {(w0,w1,w2,0) per ky} + pad
  for (int ch = threadIdx.x; ch < PL; ch += blockDim.x) {
    unsigned int r[3];
    for (int k = 0; k < 3; ++k) {
      int b0 = (int)quant87(w2[ch * 9 + 3 * k],     sw2) & 255;
      int b1 = (int)quant87(w2[ch * 9 + 3 * k + 1], sw2) & 255;
      int b2 = (int)quant87(w2[ch * 9 + 3 * k + 2], sw2) & 255;
      r[k] = (unsigned)(b0 | (b1 << 8) | (b2 << 16));
    }
    uint4 wv; wv.x = r[0]; wv.y = r[1]; wv.z = r[2]; wv.w = 0;
    *(uint4*)&wsu[W2POFF + ch * 4] = wv;
  }
  // w3 8-ch nibble words [g][32]
  for (int i = threadIdx.x; i < NG3 * COUT; i += blockDim.x) {
    int g = i / COUT, o = i - g * COUT;
    unsigned int wrd = 0;
    for (int k = 0; k < 8; ++k)
      wrd |= ((unsigned)((int)quant87(w3[o * PL + 8 * g + k], sw3) & 15)) << (4 * k);
    wsu[W3NOFF + i] = wrd;
  }
}

// quantize x to 8-ch nibble words [n][g=4][HW]; nib k of word = int4(q(ch 8g+k))
__launch_bounds__(256)
__global__ void kquantx(const float* __restrict__ x, const float* __restrict__ wsf,
                        unsigned int* __restrict__ xq4) {
  float sx = wsf[8];
  int t = blockIdx.x * 256 + threadIdx.x;            // [0, NB*4*SEGS)
  int s = t % SEGS;
  int g = (t / SEGS) & 3;
  int n = t / (SEGS * 4);
  const float* xb = x + ((size_t)n * CIN + 8 * g) * HW + s * 16;
  unsigned int* dst = xq4 + ((size_t)n * NG1 + g) * HW + s * 16;
#pragma unroll
  for (int c4 = 0; c4 < 4; ++c4) {
    unsigned int w[4] = {0u, 0u, 0u, 0u};
#pragma unroll
    for (int k = 0; k < 8; ++k) {
      float4 v = *(const float4*)(xb + (size_t)k * HW + c4 * 4);
      w[0] |= ((unsigned)((int)quant87(v.x, sx) & 15)) << (4 * k);
      w[1] |= ((unsigned)((int)quant87(v.y, sx) & 15)) << (4 * k);
      w[2] |= ((unsigned)((int)quant87(v.z, sx) & 15)) << (4 * k);
      w[3] |= ((unsigned)((int)quant87(v.w, sx) & 15)) << (4 * k);
    }
    uint4 o; o.x = w[0]; o.y = w[1]; o.z = w[2]; o.w = w[3];
    *(uint4*)(dst + c4 * 4) = o;
  }
}

// conv1 1x1 expand 32->192 + relu via sdot8. thread = 8 outs x 8 px.
template <int STORE>
__launch_bounds__(256)
__global__ void kconv1(const unsigned int* __restrict__ xq4, const float* __restrict__ wsf,
                       unsigned char* __restrict__ q1, int* __restrict__ maxslot) {
  __shared__ unsigned int lw[NG1 * 64];  // this block's 64 outs
  __shared__ unsigned char lut[2176];    // conv1 acc domain [0, 2048]
  const int* wsi = (const int*)wsf;
  const unsigned int* wsu = (const unsigned int*)wsf;
  int ogb = blockIdx.x / PXB;            // 0..2
  int pxb = blockIdx.x - ogb * PXB;
  {
    int g = threadIdx.x >> 6, ol = threadIdx.x & 63;
    lw[threadIdx.x] = wsu[W1NOFF + g * PL + ogb * 64 + ol];
  }
  if (STORE) {
    float S1 = wsf[8] * wsf[9];
    float sh1 = fmaxf((S1 * (float)wsi[4]) / 7.0f, 1e-8f);
    for (int i = threadIdx.x; i < 2176; i += 256)
      lut[i] = (unsigned char)fminf(rintf((S1 * (float)i) / sh1), 7.0f);
  }
  __syncthreads();
  int og = threadIdx.x >> 5;             // 0..7
  int pxl = threadIdx.x & 31;
  int gp = pxb * 256 + pxl * 8;          // blocks never straddle n
  int n = gp / HW, pos = gp - n * HW;
  const unsigned int* xw = xq4 + (size_t)n * NG1 * HW + pos;
  int acc[8][8] = {};
#pragma unroll
  for (int g = 0; g < NG1; ++g) {
    uint4 xa = *(const uint4*)(xw + (size_t)g * HW);
    uint4 xb = *(const uint4*)(xw + (size_t)g * HW + 4);
    uint4 wa = *(const uint4*)&lw[g * 64 + og * 8];
    uint4 wb = *(const uint4*)&lw[g * 64 + og * 8 + 4];
    unsigned int xv[8] = {xa.x, xa.y, xa.z, xa.w, xb.x, xb.y, xb.z, xb.w};
    unsigned int wv[8] = {wa.x, wa.y, wa.z, wa.w, wb.x, wb.y, wb.z, wb.w};
#pragma unroll
    for (int o = 0; o < 8; ++o)
#pragma unroll
      for (int j = 0; j < 8; ++j)
        acc[o][j] = sdot8(xv[j], wv[o], acc[o][j]);
  }
  if (!STORE) {
    int lmax = 0;
#pragma unroll
    for (int o = 0; o < 8; ++o)
#pragma unroll
      for (int j = 0; j < 8; ++j)
        lmax = max(lmax, max(acc[o][j], 0));
    block_max_commit(lmax, maxslot);
  } else {
    int cpb = ogb * 32 + og * 4;         // 4 ch-pair planes
#pragma unroll
    for (int m = 0; m < 4; ++m) {
      unsigned int b0 = 0, b1 = 0;
#pragma unroll
      for (int j = 0; j < 4; ++j) {
        int i0 = max(acc[2 * m][j], 0);
        int i1 = max(acc[2 * m + 1][j], 0);
        b0 |= ((unsigned)(lut[i0] | (lut[i1] << 4))) << (8 * j);
        int i2 = max(acc[2 * m][4 + j], 0);
        int i3 = max(acc[2 * m + 1][4 + j], 0);
        b1 |= ((unsigned)(lut[i2] | (lut[i3] << 4))) << (8 * j);
      }
      uint2 w; w.x = b0; w.y = b1;
      *(uint2*)(q1 + ((size_t)n * CP + cpb + m) * HW + pos) = w;
    }
  }
}

// depthwise 3x3 + relu: int sdot4 row-conv. thread = 8 ch (4 pair-planes) x 16 px.
// STORE=1 writes q2 as 8-ch nibble words [n][G=24][HW].
template <int STORE>
__launch_bounds__(256)
__global__ void kconv2(const unsigned char* __restrict__ q1, const float* __restrict__ wsf,
                       unsigned int* __restrict__ q2w, int* __restrict__ maxslot) {
  const int* wsi = (const int*)wsf;
  const uint4* w2p = (const uint4*)((const unsigned int*)wsf + W2POFF);
  __shared__ unsigned char lut[512];     // conv2 acc domain [0, 504]
  if (STORE) {
    float S1 = wsf[8] * wsf[9];
    float sh1 = fmaxf((S1 * (float)wsi[4]) / 7.0f, 1e-8f);
    float S2 = sh1 * wsf[10];
    float sh2 = fmaxf((S2 * (float)wsi[5]) / 7.0f, 1e-8f);
    for (int i = threadIdx.x; i < 512; i += 256)
      lut[i] = (unsigned char)fminf(rintf((S2 * (float)i) / sh2), 7.0f);
    __syncthreads();
  }
  int gid = blockIdx.x * 256 + threadIdx.x;          // [0, NB*24*SEGS)
  int nG = gid / SEGS;
  int seg = gid - nG * SEGS;
  int y = seg / SEGROW, x0 = (seg - y * SEGROW) * 16;
  int n = nG / NG3, G = nG - n * NG3;
  int cp0 = G * 4;
  const unsigned char* base = q1 + ((size_t)n * CP + cp0) * HW;
  unsigned int wacc[16];
  int lmax = 0;
  if (STORE) {
#pragma unroll
    for (int j = 0; j < 16; ++j) wacc[j] = 0u;
  }
  const unsigned int M = 0x0F0F0F0Fu;
#pragma unroll
  for (int p = 0; p < 4; ++p) {
    int ch2 = (cp0 + p) * 2;
    uint4 wv0 = w2p[ch2];
    uint4 wv1 = w2p[ch2 + 1];
    int a0[16] = {}, a1[16] = {};
#pragma unroll
    for (int ky = 0; ky < 3; ++ky) {
      int yy = y + ky - 1;
      if ((unsigned)yy >= HH) continue;
      const unsigned char* rp = base + (size_t)p * HW + yy * WID + x0;
      uint4 u = *(const uint4*)rp;
      unsigned int left  = x0 ? (unsigned int)rp[-1] : 0u;
      unsigned int right = (x0 < WID - 16) ? (unsigned int)rp[16] : 0u;
      unsigned int l0 = u.x & M, l1 = u.y & M, l2 = u.z & M, l3 = u.w & M;
      unsigned int h0 = (u.x >> 4) & M, h1 = (u.y >> 4) & M, h2 = (u.z >> 4) & M, h3 = (u.w >> 4) & M;
      unsigned int S[5], T[5];
      S[0] = (left & 15u) | (l0 << 8);
      S[1] = (l0 >> 24) | (l1 << 8);
      S[2] = (l1 >> 24) | (l2 << 8);
      S[3] = (l2 >> 24) | (l3 << 8);
      S[4] = (l3 >> 24) | ((right & 15u) << 8);
      T[0] = (left >> 4) | (h0 << 8);
      T[1] = (h0 >> 24) | (h1 << 8);
      T[2] = (h1 >> 24) | (h2 << 8);
      T[3] = (h2 >> 24) | (h3 << 8);
      T[4] = (h3 >> 24) | ((right >> 4) << 8);
      unsigned int wr0 = ky == 0 ? wv0.x : (ky == 1 ? wv0.y : wv0.z);
      unsigned int wr1 = ky == 0 ? wv1.x : (ky == 1 ? wv1.y : wv1.z);
#pragma unroll
      for (int j = 0; j < 16; ++j) {
        const int k = j >> 2, s = j & 3;
        unsigned int Wl = s ? ((S[k] >> (8 * s)) | (S[k + 1] << (32 - 8 * s))) : S[k];
        unsigned int Wh = s ? ((T[k] >> (8 * s)) | (T[k + 1] << (32 - 8 * s))) : T[k];
        a0[j] = sdot4(Wl, wr0, a0[j]);
        a1[j] = sdot4(Wh, wr1, a1[j]);
      }
    }
    if (!STORE) {
#pragma unroll
      for (int j = 0; j < 16; ++j)
        lmax = max(lmax, max(max(a0[j], 0), max(a1[j], 0)));
    } else {
#pragma unroll
      for (int j = 0; j < 16; ++j) {
        int i0 = max(a0[j], 0), i1 = max(a1[j], 0);
        wacc[j] |= ((unsigned)lut[i0] << (8 * p)) | ((unsigned)lut[i1] << (8 * p + 4));
      }
    }
  }
  if (!STORE) {
    block_max_commit(lmax, maxslot);
  } else {
    unsigned int* dst = q2w + (size_t)nG * HW + y * WID + x0;
#pragma unroll
    for (int c = 0; c < 4; ++c) {
      uint4 o; o.x = wacc[4 * c]; o.y = wacc[4 * c + 1];
      o.z = wacc[4 * c + 2]; o.w = wacc[4 * c + 3];
      *(uint4*)(dst + 4 * c) = o;
    }
  }
}

// conv3 1x1 project 192->32 + residual via sdot8 (zero unpack). thread = 8 outs x 4 px.
__launch_bounds__(256)
__global__ void kconv3(const unsigned int* __restrict__ q2w, const float* __restrict__ x,
                       const float* __restrict__ wsf, float* __restrict__ out) {
  __shared__ unsigned int lw[NG3 * COUT];  // 3 KB
  const unsigned int* wsu = (const unsigned int*)wsf;
  for (int i = threadIdx.x; i < NG3 * COUT; i += 256) lw[i] = wsu[W3NOFF + i];
  const int* wsi = (const int*)wsf;
  float S1 = wsf[8] * wsf[9];
  float sh1 = fmaxf((S1 * (float)wsi[4]) / 7.0f, 1e-8f);
  float S2 = sh1 * wsf[10];
  float sh2 = fmaxf((S2 * (float)wsi[5]) / 7.0f, 1e-8f);
  float S3 = sh2 * wsf[11];
  __syncthreads();
  int og = threadIdx.x >> 6;             // 0..3 (8 outs each)
  int lane = threadIdx.x & 63;
  int gp = blockIdx.x * 256 + lane * 4;  // blocks never straddle n
  int n = gp / HW, pos = gp - n * HW;
  const unsigned int* qp = q2w + (size_t)n * NG3 * HW + pos;
  int acc[8][4] = {};
#pragma unroll 4
  for (int g = 0; g < NG3; ++g) {
    uint4 qv = *(const uint4*)(qp + (size_t)g * HW);
    uint4 wa = *(const uint4*)&lw[g * COUT + og * 8];
    uint4 wb = *(const uint4*)&lw[g * COUT + og * 8 + 4];
    unsigned int pv[4] = {qv.x, qv.y, qv.z, qv.w};
    unsigned int wv[8] = {wa.x, wa.y, wa.z, wa.w, wb.x, wb.y, wb.z, wb.w};
#pragma unroll
    for (int o = 0; o < 8; ++o)
#pragma unroll
      for (int j = 0; j < 4; ++j)
        acc[o][j] = sdot8(pv[j], wv[o], acc[o][j]);
  }
  int ob = og * 8;
#pragma unroll
  for (int o = 0; o < 8; ++o) {
    const float* xp = x + ((size_t)n * COUT + ob + o) * HW + pos;
    float* op = out + ((size_t)n * COUT + ob + o) * HW + pos;
    float4 xv = *(const float4*)xp;
    float4 r;
    r.x = fmaf(S3, (float)acc[o][0], xv.x);
    r.y = fmaf(S3, (float)acc[o][1], xv.y);
    r.z = fmaf(S3, (float)acc[o][2], xv.z);
    r.w = fmaf(S3, (float)acc[o][3], xv.w);
    *(float4*)op = r;
  }
}

extern "C" void kernel_launch(void* const* d_in, const int* in_sizes, int n_in,
                              void* d_out, int out_size, void* d_ws, size_t ws_size,
                              hipStream_t stream) {
  const float* x  = (const float*)d_in[0];
  const float* w1 = (const float*)d_in[1];
  const float* w2 = (const float*)d_in[2];
  const float* w3 = (const float*)d_in[3];
  float* out = (float*)d_out;

  float* wsf = (float*)d_ws;
  int* wsi = (int*)d_ws;
  unsigned char* q1 = (unsigned char*)d_ws + Q1OFF_BYTES;
  unsigned int* q2w = (unsigned int*)(q1 + QBYTES);
  // xq (6.4 MB nibble words) lives in d_out's front; consumed by kconv1,
  // then kconv3 (sole final writer) overwrites the whole out buffer.
  unsigned int* xq4 = (unsigned int*)d_out;

  kzero<<<1, 64, 0, stream>>>(wsi);

  int n4 = in_sizes[0] / 4;
  kmax_x<<<1024, 256, 0, stream>>>(x, n4, wsi + 0);
  kmax_w<<<3, 256, 0, stream>>>(w1, w2, w3, wsi);
  kprep<<<1, 256, 0, stream>>>(w1, w2, w3, wsf);
  kquantx<<<NB * NG1 * SEGS / 256, 256, 0, stream>>>(x, wsf, xq4);

  kconv1<0><<<3 * PXB, 256, 0, stream>>>(xq4, wsf, q1, wsi + 4);
  kconv1<1><<<3 * PXB, 256, 0, stream>>>(xq4, wsf, q1, wsi + 4);

  int nblk2 = NB * NG3 * SEGS / 256;               // 2352
  kconv2<0><<<nblk2, 256, 0, stream>>>(q1, wsf, q2w, wsi + 5);
  kconv2<1><<<nblk2, 256, 0, stream>>>(q1, wsf, q2w, wsi + 5);

  kconv3<<<NB * HW / 256, 256, 0, stream>>>(q2w, x, wsf, out);
}

// Round 8
// 202.762 us; speedup vs baseline: 37.6578x; 1.0127x over previous
//
#include <hip/hip_runtime.h>

#define NB   32
#define CIN  32
#define PL   192
#define CP   96        // channel pairs (PL/2)
#define NG1  4         // 8-ch groups in conv1 input (32/8)
#define NG3  24        // 8-ch groups in conv3 input (192/8)
#define HH   112
#define WID  112
#define HW   12544     // 112*112
#define COUT 32
#define SEGS 784       // HW/16
#define SEGROW 7       // WID/16
#define PXB  1568      // NB*HW/256
#define RT2  392       // (HH/2)*(WID/16) row-pair tiles per (n,G)

// ws u32-offset layout
#define W2POFF 64                       // 768 u32: per ch uint4 {row0,row1,row2,0} i8-packed
#define W1NOFF (W2POFF + PL*4)          // 768 u32: w1 8-ch nibble words [g=4][192]
#define W3NOFF (W1NOFF + NG1*PL)        // 768 u32: w3 8-ch nibble words [g=24][32]
#define Q1OFF_BYTES 65536
#define QBYTES ((size_t)NB*CP*HW)       // 38,535,168 bytes per packed tensor
// scalars: wsi[0..3]=absmax bits x,w1,w2,w3; wsi[4]=conv1 int max; wsi[5]=conv2 int max
//          wsf[8..11]=scales sx,sw1,sw2,sw3

__device__ __forceinline__ int sdot4(unsigned int a, unsigned int b, int c) {
#if defined(__has_builtin) && __has_builtin(__builtin_amdgcn_sdot4)
  return __builtin_amdgcn_sdot4((int)a, (int)b, c, false);
#else
#pragma unroll
  for (int i = 0; i < 4; ++i)
    c += ((int)(a << (24 - 8 * i)) >> 24) * ((int)(b << (24 - 8 * i)) >> 24);
  return c;
#endif
}

__device__ __forceinline__ int sdot8(unsigned int a, unsigned int b, int c) {
#if defined(__has_builtin) && __has_builtin(__builtin_amdgcn_sdot8)
  return __builtin_amdgcn_sdot8((int)a, (int)b, c, false);
#else
#pragma unroll
  for (int i = 0; i < 8; ++i)
    c += ((int)(a << (28 - 4 * i)) >> 28) * ((int)(b << (28 - 4 * i)) >> 28);
  return c;
#endif
}

// 4-byte sliding window: bytes (lo.bSH .. ), i.e. ((lo>>8*SH)|(hi<<(32-8*SH)))
template <int SH>
__device__ __forceinline__ unsigned int winsh(unsigned int hi, unsigned int lo) {
#if defined(__has_builtin) && __has_builtin(__builtin_amdgcn_perm)
  const unsigned int sel = (SH == 1) ? 0x04030201u : (SH == 2) ? 0x05040302u : 0x06050403u;
  return __builtin_amdgcn_perm(hi, lo, sel);
#else
  return (lo >> (8 * SH)) | (hi << (32 - 8 * SH));
#endif
}

__device__ __forceinline__ float quant87(float v, float s) {
  return fminf(fmaxf(rintf(v / s), -8.0f), 7.0f);
}

// block-level int max -> single conditional atomic (monotone max: race-safe)
__device__ __forceinline__ void block_max_commit(int lmax, int* __restrict__ slot) {
  __shared__ int red[4];
  for (int o = 32; o; o >>= 1) lmax = max(lmax, __shfl_down(lmax, o));
  if ((threadIdx.x & 63) == 0) red[threadIdx.x >> 6] = lmax;
  __syncthreads();
  if (threadIdx.x == 0) {
    int m = max(max(red[0], red[1]), max(red[2], red[3]));
    int cur = *(const volatile int*)slot;
    if (m > cur) atomicMax(slot, m);
  }
}

__global__ void kzero(int* __restrict__ wsi) {
  if (threadIdx.x < 16) wsi[threadIdx.x] = 0;
}

__global__ void kmax_x(const float* __restrict__ x, int n4, int* __restrict__ slot) {
  const float4* x4 = (const float4*)x;
  float m = 0.f;
  for (int i = blockIdx.x * blockDim.x + threadIdx.x; i < n4; i += gridDim.x * blockDim.x) {
    float4 v = x4[i];
    m = fmaxf(fmaxf(fabsf(v.x), fabsf(v.y)), fmaxf(fmaxf(fabsf(v.z), fabsf(v.w)), m));
  }
  block_max_commit(__float_as_int(m), slot);   // non-negative: int cmp == float cmp
}

__global__ void kmax_w(const float* __restrict__ w1, const float* __restrict__ w2,
                       const float* __restrict__ w3, int* __restrict__ slots) {
  const float* p; int n;
  if (blockIdx.x == 0)      { p = w1; n = PL * CIN; }
  else if (blockIdx.x == 1) { p = w2; n = PL * 9; }
  else                      { p = w3; n = COUT * PL; }
  float m = 0.f;
  for (int i = threadIdx.x; i < n; i += blockDim.x) m = fmaxf(m, fabsf(p[i]));
  for (int o = 32; o; o >>= 1) m = fmaxf(m, __shfl_down(m, o));
  if ((threadIdx.x & 63) == 0) atomicMax(slots + 1 + blockIdx.x, __float_as_int(m));
}

__global__ void kprep(const float* __restrict__ w1, const float* __restrict__ w2,
                      const float* __restrict__ w3, float* __restrict__ wsf) {
  int* wsi = (int*)wsf;
  unsigned int* wsu = (unsigned int*)wsf;
  __shared__ float ss[4];
  if (threadIdx.x == 0) {
    float sx  = fmaxf(__int_as_float(wsi[0]) / 7.0f, 1e-8f);
    float sw1 = fmaxf(__int_as_float(wsi[1]) / 7.0f, 1e-8f);
    float sw2 = fmaxf(__int_as_float(wsi[2]) / 7.0f, 1e-8f);
    float sw3 = fmaxf(__int_as_float(wsi[3]) / 7.0f, 1e-8f);
    wsf[8] = sx; wsf[9] = sw1; wsf[10] = sw2; wsf[11] = sw3;
    ss[1] = sw1; ss[2] = sw2; ss[3] = sw3;
  }
  __syncthreads();
  float sw1 = ss[1], sw2 = ss[2], sw3 = ss[3];
  // w1 8-ch nibble words [g][192]
  for (int i = threadIdx.x; i < NG1 * PL; i += blockDim.x) {
    int g = i / PL, o = i - g * PL;
    unsigned int wrd = 0;
    for (int k = 0; k < 8; ++k)
      wrd |= ((unsigned)((int)quant87(w1[o * CIN + 8 * g + k], sw1) & 15)) << (4 * k);
    wsu[W1NOFF + i] = wrd;
  }
  // w2 i8 row words {(w0,w1,w2,0) per ky}
  for (int ch = threadIdx.x; ch < PL; ch += blockDim.x) {
    unsigned int r[3];
    for (int k = 0; k < 3; ++k) {
      int b0 = (int)quant87(w2[ch * 9 + 3 * k],     sw2) & 255;
      int b1 = (int)quant87(w2[ch * 9 + 3 * k + 1], sw2) & 255;
      int b2 = (int)quant87(w2[ch * 9 + 3 * k + 2], sw2) & 255;
      r[k] = (unsigned)(b0 | (b1 << 8) | (b2 << 16));
    }
    uint4 wv; wv.x = r[0]; wv.y = r[1]; wv.z = r[2]; wv.w = 0;
    *(uint4*)&wsu[W2POFF + ch * 4] = wv;
  }
  // w3 8-ch nibble words [g][32]
  for (int i = threadIdx.x; i < NG3 * COUT; i += blockDim.x) {
    int g = i / COUT, o = i - g * COUT;
    unsigned int wrd = 0;
    for (int k = 0; k < 8; ++k)
      wrd |= ((unsigned)((int)quant87(w3[o * PL + 8 * g + k], sw3) & 15)) << (4 * k);
    wsu[W3NOFF + i] = wrd;
  }
}

// quantize x to 8-ch nibble words [n][g=4][HW]
__launch_bounds__(256)
__global__ void kquantx(const float* __restrict__ x, const float* __restrict__ wsf,
                        unsigned int* __restrict__ xq4) {
  float sx = wsf[8];
  int t = blockIdx.x * 256 + threadIdx.x;            // [0, NB*4*SEGS)
  int s = t % SEGS;
  int g = (t / SEGS) & 3;
  int n = t / (SEGS * 4);
  const float* xb = x + ((size_t)n * CIN + 8 * g) * HW + s * 16;
  unsigned int* dst = xq4 + ((size_t)n * NG1 + g) * HW + s * 16;
#pragma unroll
  for (int c4 = 0; c4 < 4; ++c4) {
    unsigned int w[4] = {0u, 0u, 0u, 0u};
#pragma unroll
    for (int k = 0; k < 8; ++k) {
      float4 v = *(const float4*)(xb + (size_t)k * HW + c4 * 4);
      w[0] |= ((unsigned)((int)quant87(v.x, sx) & 15)) << (4 * k);
      w[1] |= ((unsigned)((int)quant87(v.y, sx) & 15)) << (4 * k);
      w[2] |= ((unsigned)((int)quant87(v.z, sx) & 15)) << (4 * k);
      w[3] |= ((unsigned)((int)quant87(v.w, sx) & 15)) << (4 * k);
    }
    uint4 o; o.x = w[0]; o.y = w[1]; o.z = w[2]; o.w = w[3];
    *(uint4*)(dst + c4 * 4) = o;
  }
}

// conv1 1x1 expand 32->192 + relu via sdot8. thread = 8 outs x 8 px.
template <int STORE>
__launch_bounds__(256)
__global__ void kconv1(const unsigned int* __restrict__ xq4, const float* __restrict__ wsf,
                       unsigned char* __restrict__ q1, int* __restrict__ maxslot) {
  __shared__ unsigned int lw[NG1 * 64];  // this block's 64 outs
  __shared__ unsigned char lut[2176];    // conv1 acc domain [0, 2048]
  const int* wsi = (const int*)wsf;
  const unsigned int* wsu = (const unsigned int*)wsf;
  int ogb = blockIdx.x / PXB;            // 0..2
  int pxb = blockIdx.x - ogb * PXB;
  {
    int g = threadIdx.x >> 6, ol = threadIdx.x & 63;
    lw[threadIdx.x] = wsu[W1NOFF + g * PL + ogb * 64 + ol];
  }
  if (STORE) {
    float S1 = wsf[8] * wsf[9];
    float sh1 = fmaxf((S1 * (float)wsi[4]) / 7.0f, 1e-8f);
    for (int i = threadIdx.x; i < 2176; i += 256)
      lut[i] = (unsigned char)fminf(rintf((S1 * (float)i) / sh1), 7.0f);
  }
  __syncthreads();
  int og = threadIdx.x >> 5;             // 0..7
  int pxl = threadIdx.x & 31;
  int gp = pxb * 256 + pxl * 8;          // blocks never straddle n
  int n = gp / HW, pos = gp - n * HW;
  const unsigned int* xw = xq4 + (size_t)n * NG1 * HW + pos;
  int acc[8][8] = {};
#pragma unroll
  for (int g = 0; g < NG1; ++g) {
    uint4 xa = *(const uint4*)(xw + (size_t)g * HW);
    uint4 xb = *(const uint4*)(xw + (size_t)g * HW + 4);
    uint4 wa = *(const uint4*)&lw[g * 64 + og * 8];
    uint4 wb = *(const uint4*)&lw[g * 64 + og * 8 + 4];
    unsigned int xv[8] = {xa.x, xa.y, xa.z, xa.w, xb.x, xb.y, xb.z, xb.w};
    unsigned int wv[8] = {wa.x, wa.y, wa.z, wa.w, wb.x, wb.y, wb.z, wb.w};
#pragma unroll
    for (int o = 0; o < 8; ++o)
#pragma unroll
      for (int j = 0; j < 8; ++j)
        acc[o][j] = sdot8(xv[j], wv[o], acc[o][j]);
  }
  if (!STORE) {
    int lmax = 0;
#pragma unroll
    for (int o = 0; o < 8; ++o)
#pragma unroll
      for (int j = 0; j < 8; ++j)
        lmax = max(lmax, max(acc[o][j], 0));
    block_max_commit(lmax, maxslot);
  } else {
    int cpb = ogb * 32 + og * 4;         // 4 ch-pair planes
#pragma unroll
    for (int m = 0; m < 4; ++m) {
      unsigned int b0 = 0, b1 = 0;
#pragma unroll
      for (int j = 0; j < 4; ++j) {
        int i0 = max(acc[2 * m][j], 0);
        int i1 = max(acc[2 * m + 1][j], 0);
        b0 |= ((unsigned)(lut[i0] | (lut[i1] << 4))) << (8 * j);
        int i2 = max(acc[2 * m][4 + j], 0);
        int i3 = max(acc[2 * m + 1][4 + j], 0);
        b1 |= ((unsigned)(lut[i2] | (lut[i3] << 4))) << (8 * j);
      }
      uint2 w; w.x = b0; w.y = b1;
      *(uint2*)(q1 + ((size_t)n * CP + cpb + m) * HW + pos) = w;
    }
  }
}

// depthwise 3x3 + relu. thread = 8 ch (4 pair-planes) x 2 out-rows x 16 px.
// Tap rows loaded once, perm-built windows dotted into both output rows.
// STORE=1 writes q2 as 8-ch nibble words [n][G=24][HW].
template <int STORE>
__launch_bounds__(256)
__global__ void kconv2(const unsigned char* __restrict__ q1, const float* __restrict__ wsf,
                       unsigned int* __restrict__ q2w, int* __restrict__ maxslot) {
  const int* wsi = (const int*)wsf;
  const uint4* w2p = (const uint4*)((const unsigned int*)wsf + W2POFF);
  __shared__ unsigned char lut[512];     // conv2 acc domain [0, 441]
  if (STORE) {
    float S1 = wsf[8] * wsf[9];
    float sh1 = fmaxf((S1 * (float)wsi[4]) / 7.0f, 1e-8f);
    float S2 = sh1 * wsf[10];
    float sh2 = fmaxf((S2 * (float)wsi[5]) / 7.0f, 1e-8f);
    for (int i = threadIdx.x; i < 512; i += 256)
      lut[i] = (unsigned char)fminf(rintf((S2 * (float)i) / sh2), 7.0f);
    __syncthreads();
  }
  int gid = blockIdx.x * 256 + threadIdx.x;          // [0, NB*NG3*RT2)
  int nG = gid / RT2;
  int t  = gid - nG * RT2;
  int r2 = t / SEGROW;                               // 0..55
  int c  = t - r2 * SEGROW;                          // 0..6
  int y0 = r2 * 2, x0 = c * 16;
  int n = nG / NG3, G = nG - n * NG3;
  int cp0 = G * 4;
  const unsigned char* base = q1 + ((size_t)n * CP + cp0) * HW;
  const unsigned int M = 0x0F0F0F0Fu;
  unsigned int w0acc[16], w1acc[16];
  if (STORE) {
#pragma unroll
    for (int j = 0; j < 16; ++j) { w0acc[j] = 0u; w1acc[j] = 0u; }
  }
  int lmax = 0;
#pragma unroll
  for (int p = 0; p < 4; ++p) {
    int ch2 = (cp0 + p) * 2;
    uint4 wv0 = w2p[ch2];
    uint4 wv1 = w2p[ch2 + 1];
    unsigned int wr0[3] = {wv0.x, wv0.y, wv0.z};
    unsigned int wr1[3] = {wv1.x, wv1.y, wv1.z};
    int a0r0[16] = {}, a1r0[16] = {}, a0r1[16] = {}, a1r1[16] = {};
#pragma unroll
    for (int R = 0; R < 4; ++R) {
      unsigned int yy = (unsigned)(y0 - 1 + R);
      bool vld = yy < (unsigned)HH;
      const unsigned char* rp = base + (size_t)p * HW + (size_t)yy * WID + x0;
      uint4 u; u.x = u.y = u.z = u.w = 0u;
      unsigned int lwr = 0u, rwr = 0u;
      if (vld) u = *(const uint4*)rp;
      if (vld && x0 > 0) lwr = *(const unsigned int*)(rp - 4);
      if (vld && x0 < WID - 16) rwr = *(const unsigned int*)(rp + 16);
      // nibble-split streams: SL[m]/SHS[m], m=0 => left word (byte3 = px x0-1)
      unsigned int SL[6], SHS[6];
      SL[0] = lwr & M;          SHS[0] = (lwr >> 4) & M;
      SL[1] = u.x & M;          SHS[1] = (u.x >> 4) & M;
      SL[2] = u.y & M;          SHS[2] = (u.y >> 4) & M;
      SL[3] = u.z & M;          SHS[3] = (u.z >> 4) & M;
      SL[4] = u.w & M;          SHS[4] = (u.w >> 4) & M;
      SL[5] = rwr & M;          SHS[5] = (rwr >> 4) & M;
#pragma unroll
      for (int j = 0; j < 16; ++j) {
        const int m = j >> 2, s = j & 3;
        unsigned int Wl, Wh;
        if (s == 1)      { Wl = SL[m + 1];                    Wh = SHS[m + 1]; }
        else if (s == 2) { Wl = winsh<1>(SL[m + 2], SL[m + 1]); Wh = winsh<1>(SHS[m + 2], SHS[m + 1]); }
        else if (s == 3) { Wl = winsh<2>(SL[m + 2], SL[m + 1]); Wh = winsh<2>(SHS[m + 2], SHS[m + 1]); }
        else             { Wl = winsh<3>(SL[m + 1], SL[m]);     Wh = winsh<3>(SHS[m + 1], SHS[m]); }
        if (R <= 2) {
          a0r0[j] = sdot4(Wl, wr0[R], a0r0[j]);
          a1r0[j] = sdot4(Wh, wr1[R], a1r0[j]);
        }
        if (R >= 1) {
          a0r1[j] = sdot4(Wl, wr0[R - 1], a0r1[j]);
          a1r1[j] = sdot4(Wh, wr1[R - 1], a1r1[j]);
        }
      }
    }
    if (!STORE) {
#pragma unroll
      for (int j = 0; j < 16; ++j) {
        lmax = max(lmax, max(a0r0[j], a1r0[j]));
        lmax = max(lmax, max(a0r1[j], a1r1[j]));
      }
    } else {
#pragma unroll
      for (int j = 0; j < 16; ++j) {
        unsigned int b0 = (unsigned)lut[max(a0r0[j], 0)] | ((unsigned)lut[max(a1r0[j], 0)] << 4);
        unsigned int b1 = (unsigned)lut[max(a0r1[j], 0)] | ((unsigned)lut[max(a1r1[j], 0)] << 4);
        w0acc[j] |= b0 << (8 * p);
        w1acc[j] |= b1 << (8 * p);
      }
    }
  }
  if (!STORE) {
    block_max_commit(max(lmax, 0), maxslot);
  } else {
    unsigned int* d0 = q2w + (size_t)nG * HW + (size_t)y0 * WID + x0;
    unsigned int* d1 = d0 + WID;
#pragma unroll
    for (int k = 0; k < 4; ++k) {
      uint4 o0; o0.x = w0acc[4 * k]; o0.y = w0acc[4 * k + 1]; o0.z = w0acc[4 * k + 2]; o0.w = w0acc[4 * k + 3];
      uint4 o1; o1.x = w1acc[4 * k]; o1.y = w1acc[4 * k + 1]; o1.z = w1acc[4 * k + 2]; o1.w = w1acc[4 * k + 3];
      *(uint4*)(d0 + 4 * k) = o0;
      *(uint4*)(d1 + 4 * k) = o1;
    }
  }
}

// conv3 1x1 project 192->32 + residual via sdot8 (zero unpack). thread = 8 outs x 4 px.
__launch_bounds__(256)
__global__ void kconv3(const unsigned int* __restrict__ q2w, const float* __restrict__ x,
                       const float* __restrict__ wsf, float* __restrict__ out) {
  __shared__ unsigned int lw[NG3 * COUT];  // 3 KB
  const unsigned int* wsu = (const unsigned int*)wsf;
  for (int i = threadIdx.x; i < NG3 * COUT; i += 256) lw[i] = wsu[W3NOFF + i];
  const int* wsi = (const int*)wsf;
  float S1 = wsf[8] * wsf[9];
  float sh1 = fmaxf((S1 * (float)wsi[4]) / 7.0f, 1e-8f);
  float S2 = sh1 * wsf[10];
  float sh2 = fmaxf((S2 * (float)wsi[5]) / 7.0f, 1e-8f);
  float S3 = sh2 * wsf[11];
  __syncthreads();
  int og = threadIdx.x >> 6;             // 0..3 (8 outs each)
  int lane = threadIdx.x & 63;
  int gp = blockIdx.x * 256 + lane * 4;  // blocks never straddle n
  int n = gp / HW, pos = gp - n * HW;
  const unsigned int* qp = q2w + (size_t)n * NG3 * HW + pos;
  int acc[8][4] = {};
#pragma unroll 4
  for (int g = 0; g < NG3; ++g) {
    uint4 qv = *(const uint4*)(qp + (size_t)g * HW);
    uint4 wa = *(const uint4*)&lw[g * COUT + og * 8];
    uint4 wb = *(const uint4*)&lw[g * COUT + og * 8 + 4];
    unsigned int pv[4] = {qv.x, qv.y, qv.z, qv.w};
    unsigned int wv[8] = {wa.x, wa.y, wa.z, wa.w, wb.x, wb.y, wb.z, wb.w};
#pragma unroll
    for (int o = 0; o < 8; ++o)
#pragma unroll
      for (int j = 0; j < 4; ++j)
        acc[o][j] = sdot8(pv[j], wv[o], acc[o][j]);
  }
  int ob = og * 8;
#pragma unroll
  for (int o = 0; o < 8; ++o) {
    const float* xp = x + ((size_t)n * COUT + ob + o) * HW + pos;
    float* op = out + ((size_t)n * COUT + ob + o) * HW + pos;
    float4 xv = *(const float4*)xp;
    float4 r;
    r.x = fmaf(S3, (float)acc[o][0], xv.x);
    r.y = fmaf(S3, (float)acc[o][1], xv.y);
    r.z = fmaf(S3, (float)acc[o][2], xv.z);
    r.w = fmaf(S3, (float)acc[o][3], xv.w);
    *(float4*)op = r;
  }
}

extern "C" void kernel_launch(void* const* d_in, const int* in_sizes, int n_in,
                              void* d_out, int out_size, void* d_ws, size_t ws_size,
                              hipStream_t stream) {
  const float* x  = (const float*)d_in[0];
  const float* w1 = (const float*)d_in[1];
  const float* w2 = (const float*)d_in[2];
  const float* w3 = (const float*)d_in[3];
  float* out = (float*)d_out;

  float* wsf = (float*)d_ws;
  int* wsi = (int*)d_ws;
  unsigned char* q1 = (unsigned char*)d_ws + Q1OFF_BYTES;
  unsigned int* q2w = (unsigned int*)(q1 + QBYTES);
  // xq (6.4 MB nibble words) lives in d_out's front; consumed by kconv1,
  // then kconv3 (sole final writer) overwrites the whole out buffer.
  unsigned int* xq4 = (unsigned int*)d_out;

  kzero<<<1, 64, 0, stream>>>(wsi);

  int n4 = in_sizes[0] / 4;
  kmax_x<<<1024, 256, 0, stream>>>(x, n4, wsi + 0);
  kmax_w<<<3, 256, 0, stream>>>(w1, w2, w3, wsi);
  kprep<<<1, 256, 0, stream>>>(w1, w2, w3, wsf);
  kquantx<<<NB * NG1 * SEGS / 256, 256, 0, stream>>>(x, wsf, xq4);

  kconv1<0><<<3 * PXB, 256, 0, stream>>>(xq4, wsf, q1, wsi + 4);
  kconv1<1><<<3 * PXB, 256, 0, stream>>>(xq4, wsf, q1, wsi + 4);

  int nblk2 = NB * NG3 * RT2 / 256;                // 1176
  kconv2<0><<<nblk2, 256, 0, stream>>>(q1, wsf, q2w, wsi + 5);
  kconv2<1><<<nblk2, 256, 0, stream>>>(q1, wsf, q2w, wsi + 5);

  kconv3<<<NB * HW / 256, 256, 0, stream>>>(q2w, x, wsf, out);
}

// Round 9
// 184.444 us; speedup vs baseline: 41.3977x; 1.0993x over previous
//
#include <hip/hip_runtime.h>

#define NB   32
#define CIN  32
#define PL   192
#define CP   96        // channel pairs (PL/2)
#define NG1  4         // 8-ch groups in conv1 input (32/8)
#define NG3  24        // 8-ch groups in conv3 input (192/8)
#define HH   112
#define WID  112
#define HW   12544     // 112*112
#define COUT 32
#define SEGS 784       // HW/16
#define SEGROW 7       // WID/16
#define PXB  1568      // NB*HW/256
#define SEG8 14        // WID/8
#define RT8  784       // (HH/2)*(WID/8) row-pair x 8px tiles per (n,G)

// ws u32-offset layout
#define W2POFF 64                       // 768 u32: per ch uint4 {row0,row1,row2,0} i8-packed
#define W1NOFF (W2POFF + PL*4)          // 768 u32: w1 8-ch nibble words [g=4][192]
#define W3NOFF (W1NOFF + NG1*PL)        // 768 u32: w3 8-ch nibble words [g=24][32]
#define Q1OFF_BYTES 65536
#define QBYTES ((size_t)NB*CP*HW)       // 38,535,168 bytes per packed tensor
// scalars: wsi[0..3]=absmax bits x,w1,w2,w3; wsi[4]=conv1 int max; wsi[5]=conv2 int max
//          wsf[8..11]=scales sx,sw1,sw2,sw3

__device__ __forceinline__ int sdot4(unsigned int a, unsigned int b, int c) {
#if defined(__has_builtin) && __has_builtin(__builtin_amdgcn_sdot4)
  return __builtin_amdgcn_sdot4((int)a, (int)b, c, false);
#else
#pragma unroll
  for (int i = 0; i < 4; ++i)
    c += ((int)(a << (24 - 8 * i)) >> 24) * ((int)(b << (24 - 8 * i)) >> 24);
  return c;
#endif
}

__device__ __forceinline__ int sdot8(unsigned int a, unsigned int b, int c) {
#if defined(__has_builtin) && __has_builtin(__builtin_amdgcn_sdot8)
  return __builtin_amdgcn_sdot8((int)a, (int)b, c, false);
#else
#pragma unroll
  for (int i = 0; i < 8; ++i)
    c += ((int)(a << (28 - 4 * i)) >> 28) * ((int)(b << (28 - 4 * i)) >> 28);
  return c;
#endif
}

// 4-byte sliding window: ((lo>>8*SH)|(hi<<(32-8*SH))) via v_perm
template <int SH>
__device__ __forceinline__ unsigned int winsh(unsigned int hi, unsigned int lo) {
#if defined(__has_builtin) && __has_builtin(__builtin_amdgcn_perm)
  const unsigned int sel = (SH == 1) ? 0x04030201u : (SH == 2) ? 0x05040302u : 0x06050403u;
  return __builtin_amdgcn_perm(hi, lo, sel);
#else
  return (lo >> (8 * SH)) | (hi << (32 - 8 * SH));
#endif
}

__device__ __forceinline__ float quant87(float v, float s) {
  return fminf(fmaxf(rintf(v / s), -8.0f), 7.0f);
}

// block-level int max -> single conditional atomic (monotone max: race-safe)
__device__ __forceinline__ void block_max_commit(int lmax, int* __restrict__ slot) {
  __shared__ int red[4];
  for (int o = 32; o; o >>= 1) lmax = max(lmax, __shfl_down(lmax, o));
  if ((threadIdx.x & 63) == 0) red[threadIdx.x >> 6] = lmax;
  __syncthreads();
  if (threadIdx.x == 0) {
    int m = max(max(red[0], red[1]), max(red[2], red[3]));
    int cur = *(const volatile int*)slot;
    if (m > cur) atomicMax(slot, m);
  }
}

__global__ void kzero(int* __restrict__ wsi) {
  if (threadIdx.x < 16) wsi[threadIdx.x] = 0;
}

__global__ void kmax_x(const float* __restrict__ x, int n4, int* __restrict__ slot) {
  const float4* x4 = (const float4*)x;
  float m = 0.f;
  for (int i = blockIdx.x * blockDim.x + threadIdx.x; i < n4; i += gridDim.x * blockDim.x) {
    float4 v = x4[i];
    m = fmaxf(fmaxf(fabsf(v.x), fabsf(v.y)), fmaxf(fmaxf(fabsf(v.z), fabsf(v.w)), m));
  }
  block_max_commit(__float_as_int(m), slot);   // non-negative: int cmp == float cmp
}

__global__ void kmax_w(const float* __restrict__ w1, const float* __restrict__ w2,
                       const float* __restrict__ w3, int* __restrict__ slots) {
  const float* p; int n;
  if (blockIdx.x == 0)      { p = w1; n = PL * CIN; }
  else if (blockIdx.x == 1) { p = w2; n = PL * 9; }
  else                      { p = w3; n = COUT * PL; }
  float m = 0.f;
  for (int i = threadIdx.x; i < n; i += blockDim.x) m = fmaxf(m, fabsf(p[i]));
  for (int o = 32; o; o >>= 1) m = fmaxf(m, __shfl_down(m, o));
  if ((threadIdx.x & 63) == 0) atomicMax(slots + 1 + blockIdx.x, __float_as_int(m));
}

__global__ void kprep(const float* __restrict__ w1, const float* __restrict__ w2,
                      const float* __restrict__ w3, float* __restrict__ wsf) {
  int* wsi = (int*)wsf;
  unsigned int* wsu = (unsigned int*)wsf;
  __shared__ float ss[4];
  if (threadIdx.x == 0) {
    float sx  = fmaxf(__int_as_float(wsi[0]) / 7.0f, 1e-8f);
    float sw1 = fmaxf(__int_as_float(wsi[1]) / 7.0f, 1e-8f);
    float sw2 = fmaxf(__int_as_float(wsi[2]) / 7.0f, 1e-8f);
    float sw3 = fmaxf(__int_as_float(wsi[3]) / 7.0f, 1e-8f);
    wsf[8] = sx; wsf[9] = sw1; wsf[10] = sw2; wsf[11] = sw3;
    ss[1] = sw1; ss[2] = sw2; ss[3] = sw3;
  }
  __syncthreads();
  float sw1 = ss[1], sw2 = ss[2], sw3 = ss[3];
  // w1 8-ch nibble words [g][192]
  for (int i = threadIdx.x; i < NG1 * PL; i += blockDim.x) {
    int g = i / PL, o = i - g * PL;
    unsigned int wrd = 0;
    for (int k = 0; k < 8; ++k)
      wrd |= ((unsigned)((int)quant87(w1[o * CIN + 8 * g + k], sw1) & 15)) << (4 * k);
    wsu[W1NOFF + i] = wrd;
  }
  // w2 i8 row words {(w0,w1,w2,0) per ky}
  for (int ch = threadIdx.x; ch < PL; ch += blockDim.x) {
    unsigned int r[3];
    for (int k = 0; k < 3; ++k) {
      int b0 = (int)quant87(w2[ch * 9 + 3 * k],     sw2) & 255;
      int b1 = (int)quant87(w2[ch * 9 + 3 * k + 1], sw2) & 255;
      int b2 = (int)quant87(w2[ch * 9 + 3 * k + 2], sw2) & 255;
      r[k] = (unsigned)(b0 | (b1 << 8) | (b2 << 16));
    }
    uint4 wv; wv.x = r[0]; wv.y = r[1]; wv.z = r[2]; wv.w = 0;
    *(uint4*)&wsu[W2POFF + ch * 4] = wv;
  }
  // w3 8-ch nibble words [g][32]
  for (int i = threadIdx.x; i < NG3 * COUT; i += blockDim.x) {
    int g = i / COUT, o = i - g * COUT;
    unsigned int wrd = 0;
    for (int k = 0; k < 8; ++k)
      wrd |= ((unsigned)((int)quant87(w3[o * PL + 8 * g + k], sw3) & 15)) << (4 * k);
    wsu[W3NOFF + i] = wrd;
  }
}

// quantize x to 8-ch nibble words [n][g=4][HW]
__launch_bounds__(256)
__global__ void kquantx(const float* __restrict__ x, const float* __restrict__ wsf,
                        unsigned int* __restrict__ xq4) {
  float sx = wsf[8];
  int t = blockIdx.x * 256 + threadIdx.x;            // [0, NB*4*SEGS)
  int s = t % SEGS;
  int g = (t / SEGS) & 3;
  int n = t / (SEGS * 4);
  const float* xb = x + ((size_t)n * CIN + 8 * g) * HW + s * 16;
  unsigned int* dst = xq4 + ((size_t)n * NG1 + g) * HW + s * 16;
#pragma unroll
  for (int c4 = 0; c4 < 4; ++c4) {
    unsigned int w[4] = {0u, 0u, 0u, 0u};
#pragma unroll
    for (int k = 0; k < 8; ++k) {
      float4 v = *(const float4*)(xb + (size_t)k * HW + c4 * 4);
      w[0] |= ((unsigned)((int)quant87(v.x, sx) & 15)) << (4 * k);
      w[1] |= ((unsigned)((int)quant87(v.y, sx) & 15)) << (4 * k);
      w[2] |= ((unsigned)((int)quant87(v.z, sx) & 15)) << (4 * k);
      w[3] |= ((unsigned)((int)quant87(v.w, sx) & 15)) << (4 * k);
    }
    uint4 o; o.x = w[0]; o.y = w[1]; o.z = w[2]; o.w = w[3];
    *(uint4*)(dst + c4 * 4) = o;
  }
}

// conv1 1x1 expand 32->192 + relu via sdot8. thread = 8 outs x 8 px.
template <int STORE>
__launch_bounds__(256)
__global__ void kconv1(const unsigned int* __restrict__ xq4, const float* __restrict__ wsf,
                       unsigned char* __restrict__ q1, int* __restrict__ maxslot) {
  __shared__ unsigned int lw[NG1 * 64];  // this block's 64 outs
  __shared__ unsigned char lut[2176];    // conv1 acc domain [0, 2048]
  const int* wsi = (const int*)wsf;
  const unsigned int* wsu = (const unsigned int*)wsf;
  int ogb = blockIdx.x / PXB;            // 0..2
  int pxb = blockIdx.x - ogb * PXB;
  {
    int g = threadIdx.x >> 6, ol = threadIdx.x & 63;
    lw[threadIdx.x] = wsu[W1NOFF + g * PL + ogb * 64 + ol];
  }
  if (STORE) {
    float S1 = wsf[8] * wsf[9];
    float sh1 = fmaxf((S1 * (float)wsi[4]) / 7.0f, 1e-8f);
    for (int i = threadIdx.x; i < 2176; i += 256)
      lut[i] = (unsigned char)fminf(rintf((S1 * (float)i) / sh1), 7.0f);
  }
  __syncthreads();
  int og = threadIdx.x >> 5;             // 0..7
  int pxl = threadIdx.x & 31;
  int gp = pxb * 256 + pxl * 8;          // blocks never straddle n
  int n = gp / HW, pos = gp - n * HW;
  const unsigned int* xw = xq4 + (size_t)n * NG1 * HW + pos;
  int acc[8][8] = {};
#pragma unroll
  for (int g = 0; g < NG1; ++g) {
    uint4 xa = *(const uint4*)(xw + (size_t)g * HW);
    uint4 xb = *(const uint4*)(xw + (size_t)g * HW + 4);
    uint4 wa = *(const uint4*)&lw[g * 64 + og * 8];
    uint4 wb = *(const uint4*)&lw[g * 64 + og * 8 + 4];
    unsigned int xv[8] = {xa.x, xa.y, xa.z, xa.w, xb.x, xb.y, xb.z, xb.w};
    unsigned int wv[8] = {wa.x, wa.y, wa.z, wa.w, wb.x, wb.y, wb.z, wb.w};
#pragma unroll
    for (int o = 0; o < 8; ++o)
#pragma unroll
      for (int j = 0; j < 8; ++j)
        acc[o][j] = sdot8(xv[j], wv[o], acc[o][j]);
  }
  if (!STORE) {
    int lmax = 0;
#pragma unroll
    for (int o = 0; o < 8; ++o)
#pragma unroll
      for (int j = 0; j < 8; ++j)
        lmax = max(lmax, max(acc[o][j], 0));
    block_max_commit(lmax, maxslot);
  } else {
    int cpb = ogb * 32 + og * 4;         // 4 ch-pair planes
#pragma unroll
    for (int m = 0; m < 4; ++m) {
      unsigned int b0 = 0, b1 = 0;
#pragma unroll
      for (int j = 0; j < 4; ++j) {
        int i0 = max(acc[2 * m][j], 0);
        int i1 = max(acc[2 * m + 1][j], 0);
        b0 |= ((unsigned)(lut[i0] | (lut[i1] << 4))) << (8 * j);
        int i2 = max(acc[2 * m][4 + j], 0);
        int i3 = max(acc[2 * m + 1][4 + j], 0);
        b1 |= ((unsigned)(lut[i2] | (lut[i3] << 4))) << (8 * j);
      }
      uint2 w; w.x = b0; w.y = b1;
      *(uint2*)(q1 + ((size_t)n * CP + cpb + m) * HW + pos) = w;
    }
  }
}

// depthwise 3x3 + relu. thread = 8 ch (4 pair-planes) x 2 out-rows x 8 px.
// Tap rows loaded once per row-pair, perm-built windows dotted into both
// output rows. Live accs kept at ~48 regs (occupancy fix vs 16-px variant).
// STORE=1 writes q2 as 8-ch nibble words [n][G=24][HW].
template <int STORE>
__launch_bounds__(256)
__global__ void kconv2(const unsigned char* __restrict__ q1, const float* __restrict__ wsf,
                       unsigned int* __restrict__ q2w, int* __restrict__ maxslot) {
  const int* wsi = (const int*)wsf;
  const uint4* w2p = (const uint4*)((const unsigned int*)wsf + W2POFF);
  __shared__ unsigned char lut[512];     // conv2 acc domain [0, 441]
  if (STORE) {
    float S1 = wsf[8] * wsf[9];
    float sh1 = fmaxf((S1 * (float)wsi[4]) / 7.0f, 1e-8f);
    float S2 = sh1 * wsf[10];
    float sh2 = fmaxf((S2 * (float)wsi[5]) / 7.0f, 1e-8f);
    for (int i = threadIdx.x; i < 512; i += 256)
      lut[i] = (unsigned char)fminf(rintf((S2 * (float)i) / sh2), 7.0f);
    __syncthreads();
  }
  int gid = blockIdx.x * 256 + threadIdx.x;          // [0, NB*NG3*RT8)
  int nG = gid / RT8;
  int t  = gid - nG * RT8;
  int r2 = t / SEG8;                                 // 0..55
  int c  = t - r2 * SEG8;                            // 0..13
  int y0 = r2 * 2, x0 = c * 8;
  int n = nG / NG3, G = nG - n * NG3;
  int cp0 = G * 4;
  const unsigned char* base = q1 + ((size_t)n * CP + cp0) * HW;
  const unsigned int M = 0x0F0F0F0Fu;
  unsigned int w0acc[8], w1acc[8];
  if (STORE) {
#pragma unroll
    for (int j = 0; j < 8; ++j) { w0acc[j] = 0u; w1acc[j] = 0u; }
  }
  int lmax = 0;
#pragma unroll
  for (int p = 0; p < 4; ++p) {
    int ch2 = (cp0 + p) * 2;
    uint4 wv0 = w2p[ch2];
    uint4 wv1 = w2p[ch2 + 1];
    unsigned int wr0[3] = {wv0.x, wv0.y, wv0.z};
    unsigned int wr1[3] = {wv1.x, wv1.y, wv1.z};
    int a0r0[8] = {}, a1r0[8] = {}, a0r1[8] = {}, a1r1[8] = {};
#pragma unroll
    for (int R = 0; R < 4; ++R) {
      unsigned int yy = (unsigned)(y0 - 1 + R);
      bool vld = yy < (unsigned)HH;
      const unsigned char* rp = base + (size_t)p * HW + (size_t)yy * WID + x0;
      uint2 u; u.x = u.y = 0u;
      unsigned int lwr = 0u, rwr = 0u;
      if (vld) u = *(const uint2*)rp;
      if (vld && c > 0) lwr = *(const unsigned int*)(rp - 4);
      if (vld && c < SEG8 - 1) rwr = *(const unsigned int*)(rp + 8);
      // nibble-split streams: word m=0 left, 1..2 body, 3 right
      unsigned int SL[4], SHS[4];
      SL[0] = lwr & M;  SHS[0] = (lwr >> 4) & M;
      SL[1] = u.x & M;  SHS[1] = (u.x >> 4) & M;
      SL[2] = u.y & M;  SHS[2] = (u.y >> 4) & M;
      SL[3] = rwr & M;  SHS[3] = (rwr >> 4) & M;
#pragma unroll
      for (int j = 0; j < 8; ++j) {
        const int m = j >> 2, s = j & 3;
        unsigned int Wl, Wh;
        if (s == 1)      { Wl = SL[m + 1];                      Wh = SHS[m + 1]; }
        else if (s == 2) { Wl = winsh<1>(SL[m + 2], SL[m + 1]); Wh = winsh<1>(SHS[m + 2], SHS[m + 1]); }
        else if (s == 3) { Wl = winsh<2>(SL[m + 2], SL[m + 1]); Wh = winsh<2>(SHS[m + 2], SHS[m + 1]); }
        else             { Wl = winsh<3>(SL[m + 1], SL[m]);     Wh = winsh<3>(SHS[m + 1], SHS[m]); }
        if (R <= 2) {
          a0r0[j] = sdot4(Wl, wr0[R], a0r0[j]);
          a1r0[j] = sdot4(Wh, wr1[R], a1r0[j]);
        }
        if (R >= 1) {
          a0r1[j] = sdot4(Wl, wr0[R - 1], a0r1[j]);
          a1r1[j] = sdot4(Wh, wr1[R - 1], a1r1[j]);
        }
      }
    }
    if (!STORE) {
#pragma unroll
      for (int j = 0; j < 8; ++j) {
        lmax = max(lmax, max(a0r0[j], a1r0[j]));
        lmax = max(lmax, max(a0r1[j], a1r1[j]));
      }
    } else {
#pragma unroll
      for (int j = 0; j < 8; ++j) {
        unsigned int b0 = (unsigned)lut[max(a0r0[j], 0)] | ((unsigned)lut[max(a1r0[j], 0)] << 4);
        unsigned int b1 = (unsigned)lut[max(a0r1[j], 0)] | ((unsigned)lut[max(a1r1[j], 0)] << 4);
        w0acc[j] |= b0 << (8 * p);
        w1acc[j] |= b1 << (8 * p);
      }
    }
  }
  if (!STORE) {
    block_max_commit(max(lmax, 0), maxslot);
  } else {
    unsigned int* d0 = q2w + (size_t)nG * HW + (size_t)y0 * WID + x0;
    unsigned int* d1 = d0 + WID;
    uint4 o;
    o.x = w0acc[0]; o.y = w0acc[1]; o.z = w0acc[2]; o.w = w0acc[3];
    *(uint4*)d0 = o;
    o.x = w0acc[4]; o.y = w0acc[5]; o.z = w0acc[6]; o.w = w0acc[7];
    *(uint4*)(d0 + 4) = o;
    o.x = w1acc[0]; o.y = w1acc[1]; o.z = w1acc[2]; o.w = w1acc[3];
    *(uint4*)d1 = o;
    o.x = w1acc[4]; o.y = w1acc[5]; o.z = w1acc[6]; o.w = w1acc[7];
    *(uint4*)(d1 + 4) = o;
  }
}

// conv3 1x1 project 192->32 + residual via sdot8 (zero unpack). thread = 8 outs x 4 px.
__launch_bounds__(256)
__global__ void kconv3(const unsigned int* __restrict__ q2w, const float* __restrict__ x,
                       const float* __restrict__ wsf, float* __restrict__ out) {
  __shared__ unsigned int lw[NG3 * COUT];  // 3 KB
  const unsigned int* wsu = (const unsigned int*)wsf;
  for (int i = threadIdx.x; i < NG3 * COUT; i += 256) lw[i] = wsu[W3NOFF + i];
  const int* wsi = (const int*)wsf;
  float S1 = wsf[8] * wsf[9];
  float sh1 = fmaxf((S1 * (float)wsi[4]) / 7.0f, 1e-8f);
  float S2 = sh1 * wsf[10];
  float sh2 = fmaxf((S2 * (float)wsi[5]) / 7.0f, 1e-8f);
  float S3 = sh2 * wsf[11];
  __syncthreads();
  int og = threadIdx.x >> 6;             // 0..3 (8 outs each)
  int lane = threadIdx.x & 63;
  int gp = blockIdx.x * 256 + lane * 4;  // blocks never straddle n
  int n = gp / HW, pos = gp - n * HW;
  const unsigned int* qp = q2w + (size_t)n * NG3 * HW + pos;
  int acc[8][4] = {};
#pragma unroll 4
  for (int g = 0; g < NG3; ++g) {
    uint4 qv = *(const uint4*)(qp + (size_t)g * HW);
    uint4 wa = *(const uint4*)&lw[g * COUT + og * 8];
    uint4 wb = *(const uint4*)&lw[g * COUT + og * 8 + 4];
    unsigned int pv[4] = {qv.x, qv.y, qv.z, qv.w};
    unsigned int wv[8] = {wa.x, wa.y, wa.z, wa.w, wb.x, wb.y, wb.z, wb.w};
#pragma unroll
    for (int o = 0; o < 8; ++o)
#pragma unroll
      for (int j = 0; j < 4; ++j)
        acc[o][j] = sdot8(pv[j], wv[o], acc[o][j]);
  }
  int ob = og * 8;
#pragma unroll
  for (int o = 0; o < 8; ++o) {
    const float* xp = x + ((size_t)n * COUT + ob + o) * HW + pos;
    float* op = out + ((size_t)n * COUT + ob + o) * HW + pos;
    float4 xv = *(const float4*)xp;
    float4 r;
    r.x = fmaf(S3, (float)acc[o][0], xv.x);
    r.y = fmaf(S3, (float)acc[o][1], xv.y);
    r.z = fmaf(S3, (float)acc[o][2], xv.z);
    r.w = fmaf(S3, (float)acc[o][3], xv.w);
    *(float4*)op = r;
  }
}

extern "C" void kernel_launch(void* const* d_in, const int* in_sizes, int n_in,
                              void* d_out, int out_size, void* d_ws, size_t ws_size,
                              hipStream_t stream) {
  const float* x  = (const float*)d_in[0];
  const float* w1 = (const float*)d_in[1];
  const float* w2 = (const float*)d_in[2];
  const float* w3 = (const float*)d_in[3];
  float* out = (float*)d_out;

  float* wsf = (float*)d_ws;
  int* wsi = (int*)d_ws;
  unsigned char* q1 = (unsigned char*)d_ws + Q1OFF_BYTES;
  unsigned int* q2w = (unsigned int*)(q1 + QBYTES);
  // xq (6.4 MB nibble words) lives in d_out's front; consumed by kconv1,
  // then kconv3 (sole final writer) overwrites the whole out buffer.
  unsigned int* xq4 = (unsigned int*)d_out;

  kzero<<<1, 64, 0, stream>>>(wsi);

  int n4 = in_sizes[0] / 4;
  kmax_x<<<1024, 256, 0, stream>>>(x, n4, wsi + 0);
  kmax_w<<<3, 256, 0, stream>>>(w1, w2, w3, wsi);
  kprep<<<1, 256, 0, stream>>>(w1, w2, w3, wsf);
  kquantx<<<NB * NG1 * SEGS / 256, 256, 0, stream>>>(x, wsf, xq4);

  kconv1<0><<<3 * PXB, 256, 0, stream>>>(xq4, wsf, q1, wsi + 4);
  kconv1<1><<<3 * PXB, 256, 0, stream>>>(xq4, wsf, q1, wsi + 4);

  int nblk2 = NB * NG3 * RT8 / 256;                // 2352
  kconv2<0><<<nblk2, 256, 0, stream>>>(q1, wsf, q2w, wsi + 5);
  kconv2<1><<<nblk2, 256, 0, stream>>>(q1, wsf, q2w, wsi + 5);

  kconv3<<<NB * HW / 256, 256, 0, stream>>>(q2w, x, wsf, out);
}